// Round 2
// baseline (1594.504 us; speedup 1.0000x reference)
//
#include <hip/hip_runtime.h>
#include <hip/hip_bf16.h>

typedef unsigned short u16;
typedef unsigned int u32;

#define NR 16384   // B*T
#define TT 4096    // T

// ---------- bf16 helpers ----------
__device__ __forceinline__ float b2f(u16 u){ return __uint_as_float(((u32)u)<<16); }
__device__ __forceinline__ u16 f2b(float f){
  u32 u = __float_as_uint(f);
  u32 r = u + 0x7fffu + ((u>>16)&1u);
  return (u16)(r>>16);
}
__device__ __forceinline__ void up2(u32 u, float&a, float&b){
  a = __uint_as_float(u<<16);
  b = __uint_as_float(u & 0xffff0000u);
}
__device__ __forceinline__ void ld8(const u16* p, float* f){
  uint4 v = *(const uint4*)p;
  up2(v.x,f[0],f[1]); up2(v.y,f[2],f[3]);
  up2(v.z,f[4],f[5]); up2(v.w,f[6],f[7]);
}
__device__ __forceinline__ float wred(float v){
  #pragma unroll
  for(int o=32;o>0;o>>=1) v += __shfl_down(v,o,64);
  return v;
}
__device__ __forceinline__ float gelu_f(float x){
  return 0.5f*x*(1.0f+erff(x*0.7071067811865475f));
}

// ---------- f32 -> bf16 conversion (n multiple of 1024) ----------
__global__ void k_cvt(const float* __restrict__ src, u16* __restrict__ dst, int n){
  int i = (blockIdx.x*256 + threadIdx.x)*4;
  if(i<n){
    float4 v = *(const float4*)(src+i);
    *(ushort4*)(dst+i) = make_ushort4(f2b(v.x),f2b(v.y),f2b(v.z),f2b(v.w));
  }
}

// ---------- K1: bl = h . w_bnd + b_bnd ; per-row sum/sumsq of h (f32 in) ----------
__global__ void k_bnd(const float* __restrict__ h, const float* __restrict__ wb,
                      const float* __restrict__ bb,
                      float* __restrict__ bl, float* __restrict__ hsum, float* __restrict__ hss){
  int wave = threadIdx.x>>6, lane = threadIdx.x&63;
  int n = blockIdx.x*4 + wave;
  const float4* hp = (const float4*)(h + (size_t)n*512 + lane*8);
  const float4* wp = (const float4*)(wb + lane*8);
  float4 h0 = hp[0], h1 = hp[1], w0 = wp[0], w1 = wp[1];
  float hv[8] = {h0.x,h0.y,h0.z,h0.w,h1.x,h1.y,h1.z,h1.w};
  float wv[8] = {w0.x,w0.y,w0.z,w0.w,w1.x,w1.y,w1.z,w1.w};
  float dot=0.f, s=0.f, ss=0.f;
  #pragma unroll
  for(int i=0;i<8;i++){ dot += hv[i]*wv[i]; s += hv[i]; ss += hv[i]*hv[i]; }
  dot = wred(dot); s = wred(s); ss = wred(ss);
  if(lane==0){ bl[n] = dot + bb[0]; hsum[n]=s; hss[n]=ss; }
}

// ---------- K2: conv9 (zero pad) + sigmoid ----------
__global__ void k_conv(const float* __restrict__ bl, const float* __restrict__ ck,
                       const float* __restrict__ cb, float* __restrict__ bsoft){
  int n = blockIdx.x*256 + threadIdx.x;
  int b = n>>12, t = n&4095;
  float acc = cb[0];
  #pragma unroll
  for(int i=0;i<9;i++){
    int tt = t-4+i;
    if(tt>=0 && tt<TT) acc += bl[(b<<12)+tt]*ck[i];
  }
  bsoft[n] = 1.0f/(1.0f+expf(-acc));
}

// ---------- K3: film_in = LN(concat(h, eb)) -> bf16 ----------
__global__ void k_filmin(const float* __restrict__ h, const float* __restrict__ bsoft,
                         const float* __restrict__ e0, const float* __restrict__ e1,
                         const float* __restrict__ g, const float* __restrict__ bb,
                         u16* __restrict__ fin){
  __shared__ float xb[640];
  __shared__ float red[8];
  int n = blockIdx.x, tid = threadIdx.x;
  float bs = bsoft[n];
  float s=0.f, ss=0.f;
  for(int idx=tid; idx<640; idx+=256){
    float v;
    if(idx<512) v = h[(size_t)n*512+idx];
    else { int j=idx-512; v = bs*e1[j] + (1.0f-bs)*e0[j]; }
    xb[idx]=v; s+=v; ss+=v*v;
  }
  s = wred(s); ss = wred(ss);
  int wave = tid>>6, lane = tid&63;
  if(lane==0){ red[wave]=s; red[wave+4]=ss; }
  __syncthreads();
  float S = red[0]+red[1]+red[2]+red[3];
  float SS = red[4]+red[5]+red[6]+red[7];
  float mu = S*(1.0f/640.0f);
  float var = SS*(1.0f/640.0f) - mu*mu;
  float rs = rsqrtf(var + 1e-5f);
  for(int idx=tid; idx<640; idx+=256){
    float v = (xb[idx]-mu)*rs*g[idx] + bb[idx];
    fin[(size_t)n*640+idx] = f2b(v);
  }
}

// ---------- generic GEMM: C = act(X @ W + bias), bf16 X/W/C, f32 bias/acc ----------
template<int ACT>
__global__ __launch_bounds__(256) void k_gemm(
    const u16* __restrict__ X, const u16* __restrict__ W, const float* __restrict__ Bv,
    u16* __restrict__ C, int M, int K, int Nc,
    long long sX, long long sW, long long sB, long long sC){
  __shared__ float Xs[32][68];  // [k][m]
  __shared__ float Ws[32][68];  // [k][n]
  int tid = threadIdx.x;
  const u16* Xb = X + (size_t)blockIdx.z*sX;
  const u16* Wb = W + (size_t)blockIdx.z*sW;
  const float* Bb = Bv + (size_t)blockIdx.z*sB;
  u16* Cb = C + (size_t)blockIdx.z*sC;
  int row0 = blockIdx.y*64, n0 = blockIdx.x*64;
  int mL = tid>>2,  kL  = (tid&3)*8;   // X tile loader: 64 rows x 32 k
  int kL2 = tid>>3, nL  = (tid&7)*8;   // W tile loader: 32 k x 64 n
  int r0 = (tid>>4)*4, c0 = (tid&15)*4;
  float acc[4][4] = {};
  for(int k0=0;k0<K;k0+=32){
    float xv[8], wv[8];
    ld8(Xb + (size_t)(row0+mL)*K + k0 + kL, xv);
    ld8(Wb + (size_t)(k0+kL2)*Nc + n0 + nL, wv);
    __syncthreads();
    #pragma unroll
    for(int j=0;j<8;j++) Xs[kL+j][mL] = xv[j];
    *(float4*)&Ws[kL2][nL]   = make_float4(wv[0],wv[1],wv[2],wv[3]);
    *(float4*)&Ws[kL2][nL+4] = make_float4(wv[4],wv[5],wv[6],wv[7]);
    __syncthreads();
    #pragma unroll
    for(int kk=0;kk<32;kk++){
      float4 av = *(const float4*)&Xs[kk][r0];
      float4 bv = *(const float4*)&Ws[kk][c0];
      float a[4] = {av.x,av.y,av.z,av.w};
      float b[4] = {bv.x,bv.y,bv.z,bv.w};
      #pragma unroll
      for(int i=0;i<4;i++)
        #pragma unroll
        for(int j=0;j<4;j++) acc[i][j] += a[i]*b[j];
    }
  }
  #pragma unroll
  for(int i=0;i<4;i++){
    int r = row0 + r0 + i;
    u16 o[4];
    #pragma unroll
    for(int j=0;j<4;j++){
      int c = n0 + c0 + j;
      float v = acc[i][j] + Bb[c];
      if(ACT) v = gelu_f(v);
      o[j] = f2b(v);
    }
    *(ushort4*)(Cb + (size_t)r*Nc + n0 + c0) = make_ushort4(o[0],o[1],o[2],o[3]);
  }
}

// ---------- K5: z = LN(h)*(1+gamma)+beta -> bf16 ----------
__global__ void k_z(const float* __restrict__ h, const float* __restrict__ hsum,
                    const float* __restrict__ hss, const float* __restrict__ g,
                    const float* __restrict__ bb, const u16* __restrict__ gb,
                    u16* __restrict__ z){
  int n = blockIdx.x, tid = threadIdx.x;
  float mu = hsum[n]*(1.0f/512.0f);
  float var = hss[n]*(1.0f/512.0f) - mu*mu;
  float rs = rsqrtf(var+1e-5f);
  for(int idx=tid; idx<512; idx+=256){
    float hv = h[(size_t)n*512+idx];
    float ln = (hv-mu)*rs*g[idx]+bb[idx];
    float gamma = b2f(gb[(size_t)n*1024+idx]);
    float beta  = b2f(gb[(size_t)n*1024+512+idx]);
    z[(size_t)n*512+idx] = f2b(ln*(1.0f+gamma)+beta);
  }
}

// ---------- score reduce: sc[k][n] = G[k][n,:] . w2[k] + b2[k] ----------
__global__ void k_scred(const u16* __restrict__ G, const float* __restrict__ w2,
                        const float* __restrict__ b2v, float* __restrict__ sc){
  int wave = threadIdx.x>>6, lane = threadIdx.x&63;
  int n = blockIdx.x*4 + wave;
  int k = blockIdx.y;
  uint2 gv = *(const uint2*)(G + ((size_t)k*NR + n)*256 + lane*4);
  float4 wv = *(const float4*)(w2 + k*256 + lane*4);
  float a0,a1,a2,a3;
  up2(gv.x,a0,a1); up2(gv.y,a2,a3);
  float s = a0*wv.x+a1*wv.y+a2*wv.z+a3*wv.w;
  s = wred(s);
  if(lane==0) sc[(size_t)k*NR+n] = s + b2v[k];
}

// ---------- K7: softmax over 10 + pooling -> x5 slots 1..4 (bf16) ----------
__global__ void k_pool(const float* __restrict__ h, const u16* __restrict__ z,
                       const float* __restrict__ sch, const float* __restrict__ scz,
                       u16* __restrict__ x5){
  __shared__ float hl[10][512];
  int n = blockIdx.x, tid = threadIdx.x;
  int b = n>>12, t = n&4095;
  for(int idx=tid; idx<10*512; idx+=256){
    int row = idx>>9, d = idx&511;
    float v;
    if(row==0) v = b2f(z[(size_t)n*512+d]);
    else {
      int tc = t-4+(row-1); tc = tc<0?0:(tc>TT-1?TT-1:tc);
      v = h[((size_t)(b<<12)+tc)*512+d];
    }
    hl[row][d]=v;
  }
  __syncthreads();
  for(int k=0;k<4;k++){
    float s[10];
    s[0] = scz[(size_t)k*NR+n];
    #pragma unroll
    for(int j=0;j<9;j++){
      int tc = t-4+j; tc = tc<0?0:(tc>TT-1?TT-1:tc);
      s[j+1] = sch[(size_t)k*NR + (b<<12)+tc];
    }
    float m = s[0];
    #pragma unroll
    for(int j=1;j<10;j++) m = fmaxf(m,s[j]);
    float e[10], sum=0.f;
    #pragma unroll
    for(int j=0;j<10;j++){ e[j]=expf(s[j]-m); sum+=e[j]; }
    float inv = 1.0f/sum;
    for(int d=tid; d<512; d+=256){
      float v=0.f;
      #pragma unroll
      for(int r=0;r<10;r++) v += e[r]*hl[r][d];
      x5[((size_t)(k+1)*NR + n)*512 + d] = f2b(v*inv);
    }
  }
}

// ---------- K9: final projection -> out f32 (116 cols) ----------
__global__ __launch_bounds__(128) void k_final(
    const u16* __restrict__ x5, const float* __restrict__ bl,
    const float* __restrict__ wq, const float* __restrict__ bq,
    const float* __restrict__ wr, const float* __restrict__ br,
    const float* __restrict__ wb_, const float* __restrict__ bb_,
    const float* __restrict__ wk, const float* __restrict__ bk,
    float* __restrict__ out){
  __shared__ __align__(16) u16 ls[4][8][512];
  int n0 = blockIdx.x*8, tid = threadIdx.x;
  for(int u=tid; u<2048; u+=128){
    int flat = u*8;
    int k = flat>>12, r = (flat>>9)&7, d = flat&511;
    *(uint4*)&ls[k][r][d] = *(const uint4*)(x5 + ((size_t)k*NR + n0 + r)*512 + d);
  }
  __syncthreads();
  int c = tid;
  const float* Wm=nullptr; const float* Bm=nullptr; int k=0, cc=0, V=0;
  if(c<64){k=0;cc=c;V=64;Wm=wq;Bm=bq;}
  else if(c<77){k=1;cc=c-64;V=13;Wm=wr;Bm=br;}
  else if(c<90){k=2;cc=c-77;V=13;Wm=wb_;Bm=bb_;}
  else if(c<115){k=3;cc=c-90;V=25;Wm=wk;Bm=bk;}
  if(c<115){
    float acc[8]={};
    for(int d=0;d<512;d++){
      float w = Wm[(size_t)d*V+cc];
      #pragma unroll
      for(int r=0;r<8;r++) acc[r] += b2f(ls[k][r][d])*w;
    }
    float bias = Bm[cc];
    #pragma unroll
    for(int r=0;r<8;r++) out[(size_t)(n0+r)*116 + c] = acc[r] + bias;
  } else if(c<123){
    int r = c-115;
    out[(size_t)(n0+r)*116 + 115] = bl[n0+r];
  }
}

// ---------- workspace layout (bytes) ----------
#define OFF_BL     0u
#define OFF_BSOFT  65536u
#define OFF_HSUM   131072u
#define OFF_HSS    196608u
#define OFF_SCH    262144u
#define OFF_SCZ    524288u
#define OFF_FIN    786432u            // bf16 NR*640
#define OFF_GB     21757952u          // bf16 NR*1024
#define OFF_Z      55312384u          // bf16 NR*512
#define OFF_HBF    72089600u          // bf16 NR*512
#define OFF_WF     88866816u          // bf16 640*1024 (film_w)
#define OFF_WA     90177536u          // bf16 4*512*256 (attn_w1)
#define OFF_WP     91226112u          // bf16 4*512*512 (proj_w1)
#define OFF_X5     93323264u          // bf16 5*NR*512  (G aliases front 2 slots)
// total 177,209,344 bytes

extern "C" void kernel_launch(void* const* d_in, const int* in_sizes, int n_in,
                              void* d_out, int out_size, void* d_ws, size_t ws_size,
                              hipStream_t stream){
  const float* h       = (const float*)d_in[0];
  const float* w_bnd   = (const float*)d_in[1];
  const float* b_bnd   = (const float*)d_in[2];
  const float* conv_k  = (const float*)d_in[3];
  const float* conv_b  = (const float*)d_in[4];
  const float* e0      = (const float*)d_in[5];
  const float* e1      = (const float*)d_in[6];
  const float* ln_in_g = (const float*)d_in[7];
  const float* ln_in_b = (const float*)d_in[8];
  const float* ln_h_g  = (const float*)d_in[9];
  const float* ln_h_b  = (const float*)d_in[10];
  const float* film_w  = (const float*)d_in[11];
  const float* film_b  = (const float*)d_in[12];
  const float* attn_w1 = (const float*)d_in[13];
  const float* attn_b1 = (const float*)d_in[14];
  const float* attn_w2 = (const float*)d_in[15];
  const float* attn_b2 = (const float*)d_in[16];
  const float* proj_w1 = (const float*)d_in[17];
  const float* proj_b1 = (const float*)d_in[18];
  const float* wq = (const float*)d_in[19];
  const float* bq = (const float*)d_in[20];
  const float* wr = (const float*)d_in[21];
  const float* br = (const float*)d_in[22];
  const float* wb_ = (const float*)d_in[23];
  const float* bb_ = (const float*)d_in[24];
  const float* wk = (const float*)d_in[25];
  const float* bk = (const float*)d_in[26];
  float* out = (float*)d_out;
  char* ws = (char*)d_ws;

  float* bl    = (float*)(ws + OFF_BL);
  float* bsoft = (float*)(ws + OFF_BSOFT);
  float* hsum  = (float*)(ws + OFF_HSUM);
  float* hss   = (float*)(ws + OFF_HSS);
  float* sch   = (float*)(ws + OFF_SCH);
  float* scz   = (float*)(ws + OFF_SCZ);
  u16* fin     = (u16*)(ws + OFF_FIN);
  u16* gb      = (u16*)(ws + OFF_GB);
  u16* z       = (u16*)(ws + OFF_Z);
  u16* hbf     = (u16*)(ws + OFF_HBF);
  u16* wfilm   = (u16*)(ws + OFF_WF);
  u16* wattn   = (u16*)(ws + OFF_WA);
  u16* wproj   = (u16*)(ws + OFF_WP);
  u16* x5      = (u16*)(ws + OFF_X5);
  u16* G       = x5;  // alias: scores consumed before pool writes slots 1..4

  // weight + h conversions to bf16
  k_cvt<<<(NR*512)/1024,256,0,stream>>>(h, hbf, NR*512);
  k_cvt<<<(640*1024)/1024,256,0,stream>>>(film_w, wfilm, 640*1024);
  k_cvt<<<(4*512*256)/1024,256,0,stream>>>(attn_w1, wattn, 4*512*256);
  k_cvt<<<(4*512*512)/1024,256,0,stream>>>(proj_w1, wproj, 4*512*512);

  k_bnd<<<NR/4,256,0,stream>>>(h,w_bnd,b_bnd,bl,hsum,hss);
  k_conv<<<NR/256,256,0,stream>>>(bl,conv_k,conv_b,bsoft);
  k_filmin<<<NR,256,0,stream>>>(h,bsoft,e0,e1,ln_in_g,ln_in_b,fin);

  dim3 gFilm(1024/64, NR/64, 1);
  k_gemm<0><<<gFilm,256,0,stream>>>(fin, wfilm, film_b, gb, NR,640,1024, 0,0,0,0);

  k_z<<<NR,256,0,stream>>>(h,hsum,hss,ln_h_g,ln_h_b,gb,z);

  dim3 gSc(256/64, NR/64, 4);
  dim3 gRed(NR/4, 4);
  k_gemm<1><<<gSc,256,0,stream>>>(hbf, wattn, attn_b1, G, NR,512,256,
                                  0, 512LL*256, 256, (long long)NR*256);
  k_scred<<<gRed,256,0,stream>>>(G, attn_w2, attn_b2, sch);
  k_gemm<1><<<gSc,256,0,stream>>>(z, wattn, attn_b1, G, NR,512,256,
                                  0, 512LL*256, 256, (long long)NR*256);
  k_scred<<<gRed,256,0,stream>>>(G, attn_w2, attn_b2, scz);

  k_pool<<<NR,256,0,stream>>>(h,z,sch,scz,x5);

  // proj1 per head: reads x5 slot k+1, writes x5 slot k (stream-serialized)
  dim3 gP(512/64, NR/64, 1);
  for(int k=0;k<4;k++){
    k_gemm<1><<<gP,256,0,stream>>>(x5 + (size_t)(k+1)*NR*512,
                                   wproj + (size_t)k*512*512,
                                   proj_b1 + (size_t)k*512,
                                   x5 + (size_t)k*NR*512,
                                   NR,512,512, 0,0,0,0);
  }

  k_final<<<NR/8,128,0,stream>>>(x5, bl, wq,bq,wr,br,wb_,bb_,wk,bk, out);
}

// Round 3
// 727.668 us; speedup vs baseline: 2.1913x; 2.1913x over previous
//
#include <hip/hip_runtime.h>
#include <hip/hip_bf16.h>

typedef unsigned short u16;
typedef unsigned int u32;

#define NR 16384   // B*T
#define TT 4096    // T

typedef __bf16 bf16_t;
typedef bf16_t bf16x8 __attribute__((ext_vector_type(8)));
typedef float f32x4 __attribute__((ext_vector_type(4)));

// ---------- bf16 helpers ----------
__device__ __forceinline__ float b2f(u16 u){ return __uint_as_float(((u32)u)<<16); }
__device__ __forceinline__ u16 f2b(float f){
  u32 u = __float_as_uint(f);
  u32 r = u + 0x7fffu + ((u>>16)&1u);
  return (u16)(r>>16);
}
__device__ __forceinline__ void up2(u32 u, float&a, float&b){
  a = __uint_as_float(u<<16);
  b = __uint_as_float(u & 0xffff0000u);
}
__device__ __forceinline__ float wred(float v){
  #pragma unroll
  for(int o=32;o>0;o>>=1) v += __shfl_down(v,o,64);
  return v;
}
__device__ __forceinline__ float gelu_f(float x){
  return 0.5f*x*(1.0f+erff(x*0.7071067811865475f));
}
__device__ __forceinline__ void gl_lds(const void* g, void* l){
  __builtin_amdgcn_global_load_lds(
      (__attribute__((address_space(1))) void*)(void*)g,
      (__attribute__((address_space(3))) void*)l, 16, 0, 0);
}

// ---------- f32 -> bf16 conversion (n multiple of 1024) ----------
__global__ void k_cvt(const float* __restrict__ src, u16* __restrict__ dst, int n){
  int i = (blockIdx.x*256 + threadIdx.x)*4;
  if(i<n){
    float4 v = *(const float4*)(src+i);
    *(ushort4*)(dst+i) = make_ushort4(f2b(v.x),f2b(v.y),f2b(v.z),f2b(v.w));
  }
}

// ---------- transpose-convert: src f32 [K][N] -> dst bf16 [N][K] ----------
__global__ void k_tw(const float* __restrict__ src, u16* __restrict__ dst,
                     int K, int N, long long sS, long long sD){
  __shared__ float t[32][33];
  const float* S = src + (size_t)blockIdx.z*sS;
  u16* D = dst + (size_t)blockIdx.z*sD;
  int k0 = blockIdx.y*32, n0 = blockIdx.x*32;
  int r = threadIdx.x>>5, c = threadIdx.x&31;
  #pragma unroll
  for(int p=0;p<4;p++) t[r+p*8][c] = S[(size_t)(k0+r+p*8)*N + n0 + c];
  __syncthreads();
  #pragma unroll
  for(int p=0;p<4;p++) D[(size_t)(n0+r+p*8)*K + k0 + c] = f2b(t[c][r+p*8]);
}

// ---------- K1: bl = h . w_bnd + b_bnd ; per-row sum/sumsq of h (f32 in) ----------
__global__ void k_bnd(const float* __restrict__ h, const float* __restrict__ wb,
                      const float* __restrict__ bb,
                      float* __restrict__ bl, float* __restrict__ hsum, float* __restrict__ hss){
  int wave = threadIdx.x>>6, lane = threadIdx.x&63;
  int n = blockIdx.x*4 + wave;
  const float4* hp = (const float4*)(h + (size_t)n*512 + lane*8);
  const float4* wp = (const float4*)(wb + lane*8);
  float4 h0 = hp[0], h1 = hp[1], w0 = wp[0], w1 = wp[1];
  float hv[8] = {h0.x,h0.y,h0.z,h0.w,h1.x,h1.y,h1.z,h1.w};
  float wv[8] = {w0.x,w0.y,w0.z,w0.w,w1.x,w1.y,w1.z,w1.w};
  float dot=0.f, s=0.f, ss=0.f;
  #pragma unroll
  for(int i=0;i<8;i++){ dot += hv[i]*wv[i]; s += hv[i]; ss += hv[i]*hv[i]; }
  dot = wred(dot); s = wred(s); ss = wred(ss);
  if(lane==0){ bl[n] = dot + bb[0]; hsum[n]=s; hss[n]=ss; }
}

// ---------- K2: conv9 (zero pad) + sigmoid ----------
__global__ void k_conv(const float* __restrict__ bl, const float* __restrict__ ck,
                       const float* __restrict__ cb, float* __restrict__ bsoft){
  int n = blockIdx.x*256 + threadIdx.x;
  int b = n>>12, t = n&4095;
  float acc = cb[0];
  #pragma unroll
  for(int i=0;i<9;i++){
    int tt = t-4+i;
    if(tt>=0 && tt<TT) acc += bl[(b<<12)+tt]*ck[i];
  }
  bsoft[n] = 1.0f/(1.0f+expf(-acc));
}

// ---------- K3: film_in = LN(concat(h, eb)) -> bf16 ----------
__global__ void k_filmin(const float* __restrict__ h, const float* __restrict__ bsoft,
                         const float* __restrict__ e0, const float* __restrict__ e1,
                         const float* __restrict__ g, const float* __restrict__ bb,
                         u16* __restrict__ fin){
  __shared__ float xb[640];
  __shared__ float red[8];
  int n = blockIdx.x, tid = threadIdx.x;
  float bs = bsoft[n];
  float s=0.f, ss=0.f;
  for(int idx=tid; idx<640; idx+=256){
    float v;
    if(idx<512) v = h[(size_t)n*512+idx];
    else { int j=idx-512; v = bs*e1[j] + (1.0f-bs)*e0[j]; }
    xb[idx]=v; s+=v; ss+=v*v;
  }
  s = wred(s); ss = wred(ss);
  int wave = tid>>6, lane = tid&63;
  if(lane==0){ red[wave]=s; red[wave+4]=ss; }
  __syncthreads();
  float S = red[0]+red[1]+red[2]+red[3];
  float SS = red[4]+red[5]+red[6]+red[7];
  float mu = S*(1.0f/640.0f);
  float var = SS*(1.0f/640.0f) - mu*mu;
  float rs = rsqrtf(var + 1e-5f);
  for(int idx=tid; idx<640; idx+=256){
    float v = (xb[idx]-mu)*rs*g[idx] + bb[idx];
    fin[(size_t)n*640+idx] = f2b(v);
  }
}

// ---------- MFMA GEMM: C = act(X @ W + bias) ----------
// X: M x K bf16 row-major. WT: N x K bf16 row-major (W transposed).
// C: M x N bf16. bias f32 per column. M multiple of 128, N of 128, K of 32.
template<int ACT>
__global__ __launch_bounds__(256) void k_mgemm(
    const u16* __restrict__ X, const u16* __restrict__ WT, const float* __restrict__ Bv,
    u16* __restrict__ C, int K, int Nc,
    long long sX, long long sW, long long sB, long long sC){
  __shared__ __align__(16) u16 As[128*32];
  __shared__ __align__(16) u16 Bs[128*32];
  int tid = threadIdx.x;
  int wave = tid>>6, lane = tid&63;
  const u16* Xb = X + (size_t)blockIdx.z*sX;
  const u16* Wb = WT + (size_t)blockIdx.z*sW;
  const float* Bb = Bv + (size_t)blockIdx.z*sB;
  u16* Cb = C + (size_t)blockIdx.z*sC;
  int row0 = blockIdx.y*128, col0 = blockIdx.x*128;
  int wr = (wave>>1)*64, wc = (wave&1)*64;
  int lrow = lane>>2;            // 0..15 (4 lanes per 32-elem row)
  int lcol = (lane&3)*8;         // k element offset within row
  int m15 = lane&15, q = lane>>4;
  f32x4 acc[4][4] = {};
  for(int k0=0;k0<K;k0+=32){
    // stage A rows [wave*32, wave*32+32), 2 DMA insts of 16 rows each
    const u16* ga = Xb + (size_t)(row0 + wave*32 + lrow)*K + k0 + lcol;
    u16* la = As + wave*32*32;
    gl_lds(ga, la);
    gl_lds(ga + (size_t)16*K, la + 16*32);
    const u16* gw = Wb + (size_t)(col0 + wave*32 + lrow)*K + k0 + lcol;
    u16* lb = Bs + wave*32*32;
    gl_lds(gw, lb);
    gl_lds(gw + (size_t)16*K, lb + 16*32);
    __syncthreads();
    bf16x8 af[4], bfr[4];
    #pragma unroll
    for(int i=0;i<4;i++){
      af[i]  = *(const bf16x8*)&As[(wr + i*16 + m15)*32 + q*8];
      bfr[i] = *(const bf16x8*)&Bs[(wc + i*16 + m15)*32 + q*8];
    }
    #pragma unroll
    for(int i=0;i<4;i++)
      #pragma unroll
      for(int j=0;j<4;j++)
        acc[i][j] = __builtin_amdgcn_mfma_f32_16x16x32_bf16(af[i], bfr[j], acc[i][j], 0,0,0);
    __syncthreads();
  }
  // epilogue: D layout col=lane&15, row=quad*4+reg
  #pragma unroll
  for(int j=0;j<4;j++){
    int cg = col0 + wc + j*16 + m15;
    float bias = Bb[cg];
    #pragma unroll
    for(int i=0;i<4;i++){
      int rbase = row0 + wr + i*16 + q*4;
      #pragma unroll
      for(int r=0;r<4;r++){
        float v = acc[i][j][r] + bias;
        if(ACT) v = gelu_f(v);
        Cb[(size_t)(rbase+r)*Nc + cg] = f2b(v);
      }
    }
  }
}

// ---------- K5: z = LN(h)*(1+gamma)+beta -> bf16 ----------
__global__ void k_z(const float* __restrict__ h, const float* __restrict__ hsum,
                    const float* __restrict__ hss, const float* __restrict__ g,
                    const float* __restrict__ bb, const u16* __restrict__ gb,
                    u16* __restrict__ z){
  int n = blockIdx.x, tid = threadIdx.x;
  float mu = hsum[n]*(1.0f/512.0f);
  float var = hss[n]*(1.0f/512.0f) - mu*mu;
  float rs = rsqrtf(var+1e-5f);
  for(int idx=tid; idx<512; idx+=256){
    float hv = h[(size_t)n*512+idx];
    float ln = (hv-mu)*rs*g[idx]+bb[idx];
    float gamma = b2f(gb[(size_t)n*1024+idx]);
    float beta  = b2f(gb[(size_t)n*1024+512+idx]);
    z[(size_t)n*512+idx] = f2b(ln*(1.0f+gamma)+beta);
  }
}

// ---------- score reduce: sc[k][n] = G[k][n,:] . w2[k] + b2[k] ----------
__global__ void k_scred(const u16* __restrict__ G, const float* __restrict__ w2,
                        const float* __restrict__ b2v, float* __restrict__ sc){
  int wave = threadIdx.x>>6, lane = threadIdx.x&63;
  int n = blockIdx.x*4 + wave;
  int k = blockIdx.y;
  uint2 gv = *(const uint2*)(G + ((size_t)k*NR + n)*256 + lane*4);
  float4 wv = *(const float4*)(w2 + k*256 + lane*4);
  float a0,a1,a2,a3;
  up2(gv.x,a0,a1); up2(gv.y,a2,a3);
  float s = a0*wv.x+a1*wv.y+a2*wv.z+a3*wv.w;
  s = wred(s);
  if(lane==0) sc[(size_t)k*NR+n] = s + b2v[k];
}

// ---------- K7: softmax over 10 + pooling -> x5 slots 1..4 (bf16) ----------
__global__ void k_pool(const float* __restrict__ h, const u16* __restrict__ z,
                       const float* __restrict__ sch, const float* __restrict__ scz,
                       u16* __restrict__ x5){
  __shared__ float hl[10][512];
  int n = blockIdx.x, tid = threadIdx.x;
  int b = n>>12, t = n&4095;
  for(int idx=tid; idx<10*512; idx+=256){
    int row = idx>>9, d = idx&511;
    float v;
    if(row==0) v = b2f(z[(size_t)n*512+d]);
    else {
      int tc = t-4+(row-1); tc = tc<0?0:(tc>TT-1?TT-1:tc);
      v = h[((size_t)(b<<12)+tc)*512+d];
    }
    hl[row][d]=v;
  }
  __syncthreads();
  for(int k=0;k<4;k++){
    float s[10];
    s[0] = scz[(size_t)k*NR+n];
    #pragma unroll
    for(int j=0;j<9;j++){
      int tc = t-4+j; tc = tc<0?0:(tc>TT-1?TT-1:tc);
      s[j+1] = sch[(size_t)k*NR + (b<<12)+tc];
    }
    float m = s[0];
    #pragma unroll
    for(int j=1;j<10;j++) m = fmaxf(m,s[j]);
    float e[10], sum=0.f;
    #pragma unroll
    for(int j=0;j<10;j++){ e[j]=expf(s[j]-m); sum+=e[j]; }
    float inv = 1.0f/sum;
    for(int d=tid; d<512; d+=256){
      float v=0.f;
      #pragma unroll
      for(int r=0;r<10;r++) v += e[r]*hl[r][d];
      x5[((size_t)(k+1)*NR + n)*512 + d] = f2b(v*inv);
    }
  }
}

// ---------- K9: final projection -> out f32 (116 cols) ----------
__global__ __launch_bounds__(128) void k_final(
    const u16* __restrict__ x5, const float* __restrict__ bl,
    const float* __restrict__ wq, const float* __restrict__ bq,
    const float* __restrict__ wr, const float* __restrict__ br,
    const float* __restrict__ wb_, const float* __restrict__ bb_,
    const float* __restrict__ wk, const float* __restrict__ bk,
    float* __restrict__ out){
  __shared__ __align__(16) u16 ls[4][8][512];
  int n0 = blockIdx.x*8, tid = threadIdx.x;
  for(int u=tid; u<2048; u+=128){
    int flat = u*8;
    int k = flat>>12, r = (flat>>9)&7, d = flat&511;
    *(uint4*)&ls[k][r][d] = *(const uint4*)(x5 + ((size_t)k*NR + n0 + r)*512 + d);
  }
  __syncthreads();
  int c = tid;
  const float* Wm=nullptr; const float* Bm=nullptr; int k=0, cc=0, V=0;
  if(c<64){k=0;cc=c;V=64;Wm=wq;Bm=bq;}
  else if(c<77){k=1;cc=c-64;V=13;Wm=wr;Bm=br;}
  else if(c<90){k=2;cc=c-77;V=13;Wm=wb_;Bm=bb_;}
  else if(c<115){k=3;cc=c-90;V=25;Wm=wk;Bm=bk;}
  if(c<115){
    float acc[8]={};
    for(int d=0;d<512;d++){
      float w = Wm[(size_t)d*V+cc];
      #pragma unroll
      for(int r=0;r<8;r++) acc[r] += b2f(ls[k][r][d])*w;
    }
    float bias = Bm[cc];
    #pragma unroll
    for(int r=0;r<8;r++) out[(size_t)(n0+r)*116 + c] = acc[r] + bias;
  } else if(c<123){
    int r = c-115;
    out[(size_t)(n0+r)*116 + 115] = bl[n0+r];
  }
}

// ---------- workspace layout (bytes) ----------
#define OFF_BL     0u
#define OFF_BSOFT  65536u
#define OFF_HSUM   131072u
#define OFF_HSS    196608u
#define OFF_SCH    262144u
#define OFF_SCZ    524288u
#define OFF_FIN    786432u            // bf16 NR*640
#define OFF_GB     21757952u          // bf16 NR*1024
#define OFF_Z      55312384u          // bf16 NR*512
#define OFF_HBF    72089600u          // bf16 NR*512
#define OFF_WF     88866816u          // bf16 1024*640 (film_w^T)
#define OFF_WA     90177536u          // bf16 4*256*512 (attn_w1^T)
#define OFF_WP     91226112u          // bf16 4*512*512 (proj_w1^T)
#define OFF_X5     93323264u          // bf16 5*NR*512  (G aliases front 2 slots)
// total 177,209,344 bytes

extern "C" void kernel_launch(void* const* d_in, const int* in_sizes, int n_in,
                              void* d_out, int out_size, void* d_ws, size_t ws_size,
                              hipStream_t stream){
  const float* h       = (const float*)d_in[0];
  const float* w_bnd   = (const float*)d_in[1];
  const float* b_bnd   = (const float*)d_in[2];
  const float* conv_k  = (const float*)d_in[3];
  const float* conv_b  = (const float*)d_in[4];
  const float* e0      = (const float*)d_in[5];
  const float* e1      = (const float*)d_in[6];
  const float* ln_in_g = (const float*)d_in[7];
  const float* ln_in_b = (const float*)d_in[8];
  const float* ln_h_g  = (const float*)d_in[9];
  const float* ln_h_b  = (const float*)d_in[10];
  const float* film_w  = (const float*)d_in[11];
  const float* film_b  = (const float*)d_in[12];
  const float* attn_w1 = (const float*)d_in[13];
  const float* attn_b1 = (const float*)d_in[14];
  const float* attn_w2 = (const float*)d_in[15];
  const float* attn_b2 = (const float*)d_in[16];
  const float* proj_w1 = (const float*)d_in[17];
  const float* proj_b1 = (const float*)d_in[18];
  const float* wq = (const float*)d_in[19];
  const float* bq = (const float*)d_in[20];
  const float* wr = (const float*)d_in[21];
  const float* br = (const float*)d_in[22];
  const float* wb_ = (const float*)d_in[23];
  const float* bb_ = (const float*)d_in[24];
  const float* wk = (const float*)d_in[25];
  const float* bk = (const float*)d_in[26];
  float* out = (float*)d_out;
  char* ws = (char*)d_ws;

  float* bl    = (float*)(ws + OFF_BL);
  float* bsoft = (float*)(ws + OFF_BSOFT);
  float* hsum  = (float*)(ws + OFF_HSUM);
  float* hss   = (float*)(ws + OFF_HSS);
  float* sch   = (float*)(ws + OFF_SCH);
  float* scz   = (float*)(ws + OFF_SCZ);
  u16* fin     = (u16*)(ws + OFF_FIN);
  u16* gb      = (u16*)(ws + OFF_GB);
  u16* z       = (u16*)(ws + OFF_Z);
  u16* hbf     = (u16*)(ws + OFF_HBF);
  u16* wfilm   = (u16*)(ws + OFF_WF);
  u16* wattn   = (u16*)(ws + OFF_WA);
  u16* wproj   = (u16*)(ws + OFF_WP);
  u16* x5      = (u16*)(ws + OFF_X5);
  u16* G       = x5;  // alias: scores consumed before pool writes slots 1..4

  // weight transpose-convert + h convert to bf16
  k_cvt<<<(NR*512)/1024,256,0,stream>>>(h, hbf, NR*512);
  {
    dim3 g(1024/32, 640/32, 1);
    k_tw<<<g,256,0,stream>>>(film_w, wfilm, 640, 1024, 0, 0);
  }
  {
    dim3 g(256/32, 512/32, 4);
    k_tw<<<g,256,0,stream>>>(attn_w1, wattn, 512, 256, 512LL*256, 256LL*512);
  }
  {
    dim3 g(512/32, 512/32, 4);
    k_tw<<<g,256,0,stream>>>(proj_w1, wproj, 512, 512, 512LL*512, 512LL*512);
  }

  k_bnd<<<NR/4,256,0,stream>>>(h,w_bnd,b_bnd,bl,hsum,hss);
  k_conv<<<NR/256,256,0,stream>>>(bl,conv_k,conv_b,bsoft);
  k_filmin<<<NR,256,0,stream>>>(h,bsoft,e0,e1,ln_in_g,ln_in_b,fin);

  dim3 gFilm(1024/128, NR/128, 1);
  k_mgemm<0><<<gFilm,256,0,stream>>>(fin, wfilm, film_b, gb, 640, 1024, 0,0,0,0);

  k_z<<<NR,256,0,stream>>>(h,hsum,hss,ln_h_g,ln_h_b,gb,z);

  dim3 gSc(256/128, NR/128, 4);
  dim3 gRed(NR/4, 4);
  k_mgemm<1><<<gSc,256,0,stream>>>(hbf, wattn, attn_b1, G, 512, 256,
                                   0, 256LL*512, 256, (long long)NR*256);
  k_scred<<<gRed,256,0,stream>>>(G, attn_w2, attn_b2, sch);
  k_mgemm<1><<<gSc,256,0,stream>>>(z, wattn, attn_b1, G, 512, 256,
                                   0, 256LL*512, 256, (long long)NR*256);
  k_scred<<<gRed,256,0,stream>>>(G, attn_w2, attn_b2, scz);

  k_pool<<<NR,256,0,stream>>>(h,z,sch,scz,x5);

  // proj1 per head: reads x5 slot k+1, writes x5 slot k (stream-serialized)
  dim3 gP(512/128, NR/128, 1);
  for(int k=0;k<4;k++){
    k_mgemm<1><<<gP,256,0,stream>>>(x5 + (size_t)(k+1)*NR*512,
                                    wproj + (size_t)k*512*512,
                                    proj_b1 + (size_t)k*512,
                                    x5 + (size_t)k*NR*512,
                                    512, 512, 0,0,0,0);
  }

  k_final<<<NR/8,128,0,stream>>>(x5, bl, wq,bq,wr,br,wb_,bb_,wk,bk, out);
}

// Round 4
// 557.125 us; speedup vs baseline: 2.8620x; 1.3061x over previous
//
#include <hip/hip_runtime.h>
#include <hip/hip_bf16.h>

typedef unsigned short u16;
typedef unsigned int u32;

#define NR 16384   // B*T
#define TT 4096    // T

typedef __bf16 bf16_t;
typedef bf16_t bf16x8 __attribute__((ext_vector_type(8)));
typedef float f32x4 __attribute__((ext_vector_type(4)));

// ---------- bf16 helpers ----------
__device__ __forceinline__ float b2f(u16 u){ return __uint_as_float(((u32)u)<<16); }
__device__ __forceinline__ u16 f2b(float f){
  u32 u = __float_as_uint(f);
  u32 r = u + 0x7fffu + ((u>>16)&1u);
  return (u16)(r>>16);
}
__device__ __forceinline__ void up2(u32 u, float&a, float&b){
  a = __uint_as_float(u<<16);
  b = __uint_as_float(u & 0xffff0000u);
}
__device__ __forceinline__ float wred(float v){
  #pragma unroll
  for(int o=32;o>0;o>>=1) v += __shfl_down(v,o,64);
  return v;
}
__device__ __forceinline__ float gelu_f(float x){
  return 0.5f*x*(1.0f+erff(x*0.7071067811865475f));
}
__device__ __forceinline__ void gl_lds(const void* g, void* l){
  __builtin_amdgcn_global_load_lds(
      (__attribute__((address_space(1))) void*)(void*)g,
      (__attribute__((address_space(3))) void*)l, 16, 0, 0);
}

// ---------- f32 -> bf16 conversion ----------
__global__ void k_cvt(const float* __restrict__ src, u16* __restrict__ dst, int n){
  int i = (blockIdx.x*256 + threadIdx.x)*4;
  if(i<n){
    float4 v = *(const float4*)(src+i);
    *(ushort4*)(dst+i) = make_ushort4(f2b(v.x),f2b(v.y),f2b(v.z),f2b(v.w));
  }
}

// ---------- transpose-convert: src f32 [K][N] -> dst bf16 [N][K] ----------
__global__ void k_tw(const float* __restrict__ src, u16* __restrict__ dst,
                     int K, int N, long long sS, long long sD){
  __shared__ float t[32][33];
  const float* S = src + (size_t)blockIdx.z*sS;
  u16* D = dst + (size_t)blockIdx.z*sD;
  int k0 = blockIdx.y*32, n0 = blockIdx.x*32;
  int r = threadIdx.x>>5, c = threadIdx.x&31;
  #pragma unroll
  for(int p=0;p<4;p++) t[r+p*8][c] = S[(size_t)(k0+r+p*8)*N + n0 + c];
  __syncthreads();
  #pragma unroll
  for(int p=0;p<4;p++) D[(size_t)(n0+r+p*8)*K + k0 + c] = f2b(t[c][r+p*8]);
}

// ---------- build block-diagonal W2^T [128][2048] + bias2[128] ----------
__global__ void k_wbig(const float* __restrict__ wq, const float* __restrict__ bq,
                       const float* __restrict__ wr, const float* __restrict__ br,
                       const float* __restrict__ wb_, const float* __restrict__ bb_,
                       const float* __restrict__ wk, const float* __restrict__ bk,
                       u16* __restrict__ WT, float* __restrict__ bias2){
  int c = blockIdx.x, tid = threadIdx.x;
  const float* Wm=nullptr; const float* Bm=nullptr; int k=0,j=0,V=0;
  if(c<64){k=0;j=c;V=64;Wm=wq;Bm=bq;}
  else if(c<77){k=1;j=c-64;V=13;Wm=wr;Bm=br;}
  else if(c<90){k=2;j=c-77;V=13;Wm=wb_;Bm=bb_;}
  else if(c<115){k=3;j=c-90;V=25;Wm=wk;Bm=bk;}
  for(int kk=tid;kk<2048;kk+=256){
    float v = 0.f;
    if(c<115 && (kk>>9)==k) v = Wm[(size_t)(kk&511)*V + j];
    WT[(size_t)c*2048+kk] = f2b(v);
  }
  if(tid==0) bias2[c] = (c<115) ? Bm[j] : 0.f;
}

// ---------- K1: bl = h . w_bnd + b_bnd ; per-row sum/sumsq of h (f32 in) ----------
__global__ void k_bnd(const float* __restrict__ h, const float* __restrict__ wb,
                      const float* __restrict__ bb,
                      float* __restrict__ bl, float* __restrict__ hsum, float* __restrict__ hss){
  int wave = threadIdx.x>>6, lane = threadIdx.x&63;
  int n = blockIdx.x*4 + wave;
  const float4* hp = (const float4*)(h + (size_t)n*512 + lane*8);
  const float4* wp = (const float4*)(wb + lane*8);
  float4 h0 = hp[0], h1 = hp[1], w0 = wp[0], w1 = wp[1];
  float hv[8] = {h0.x,h0.y,h0.z,h0.w,h1.x,h1.y,h1.z,h1.w};
  float wv[8] = {w0.x,w0.y,w0.z,w0.w,w1.x,w1.y,w1.z,w1.w};
  float dot=0.f, s=0.f, ss=0.f;
  #pragma unroll
  for(int i=0;i<8;i++){ dot += hv[i]*wv[i]; s += hv[i]; ss += hv[i]*hv[i]; }
  dot = wred(dot); s = wred(s); ss = wred(ss);
  if(lane==0){ bl[n] = dot + bb[0]; hsum[n]=s; hss[n]=ss; }
}

// ---------- K2: conv9 (zero pad) + sigmoid ----------
__global__ void k_conv(const float* __restrict__ bl, const float* __restrict__ ck,
                       const float* __restrict__ cb, float* __restrict__ bsoft){
  int n = blockIdx.x*256 + threadIdx.x;
  int b = n>>12, t = n&4095;
  float acc = cb[0];
  #pragma unroll
  for(int i=0;i<9;i++){
    int tt = t-4+i;
    if(tt>=0 && tt<TT) acc += bl[(b<<12)+tt]*ck[i];
  }
  bsoft[n] = 1.0f/(1.0f+expf(-acc));
}

// ---------- K3: film_in = LN(concat(h, eb)) -> bf16 ----------
__global__ void k_filmin(const float* __restrict__ h, const float* __restrict__ bsoft,
                         const float* __restrict__ e0, const float* __restrict__ e1,
                         const float* __restrict__ g, const float* __restrict__ bb,
                         u16* __restrict__ fin){
  __shared__ float xb[640];
  __shared__ float red[8];
  int n = blockIdx.x, tid = threadIdx.x;
  float bs = bsoft[n];
  float s=0.f, ss=0.f;
  for(int idx=tid; idx<640; idx+=256){
    float v;
    if(idx<512) v = h[(size_t)n*512+idx];
    else { int j=idx-512; v = bs*e1[j] + (1.0f-bs)*e0[j]; }
    xb[idx]=v; s+=v; ss+=v*v;
  }
  s = wred(s); ss = wred(ss);
  int wave = tid>>6, lane = tid&63;
  if(lane==0){ red[wave]=s; red[wave+4]=ss; }
  __syncthreads();
  float S = red[0]+red[1]+red[2]+red[3];
  float SS = red[4]+red[5]+red[6]+red[7];
  float mu = S*(1.0f/640.0f);
  float var = SS*(1.0f/640.0f) - mu*mu;
  float rs = rsqrtf(var + 1e-5f);
  for(int idx=tid; idx<640; idx+=256){
    float v = (xb[idx]-mu)*rs*g[idx] + bb[idx];
    fin[(size_t)n*640+idx] = f2b(v);
  }
}

// ---------- MFMA GEMM: C = act(X @ W + bias) ----------
// X: M x K bf16 row-major. WT: N x K bf16 (W transposed). C: M x N bf16 (ld = ldC).
template<int ACT>
__global__ __launch_bounds__(256) void k_mgemm(
    const u16* __restrict__ X, const u16* __restrict__ WT, const float* __restrict__ Bv,
    u16* __restrict__ C, int K, int Nc, int ldC,
    long long sX, long long sW, long long sB, long long sC){
  __shared__ __align__(16) u16 As[128*32];
  __shared__ __align__(16) u16 Bs[128*32];
  int tid = threadIdx.x;
  int wave = tid>>6, lane = tid&63;
  const u16* Xb = X + (size_t)blockIdx.z*sX;
  const u16* Wb = WT + (size_t)blockIdx.z*sW;
  const float* Bb = Bv + (size_t)blockIdx.z*sB;
  u16* Cb = C + (size_t)blockIdx.z*sC;
  int row0 = blockIdx.y*128, col0 = blockIdx.x*128;
  int wr = (wave>>1)*64, wc = (wave&1)*64;
  int lrow = lane>>2;            // 0..15
  int lcol = (lane&3)*8;         // k offset
  int m15 = lane&15, q = lane>>4;
  f32x4 acc[4][4] = {};
  for(int k0=0;k0<K;k0+=32){
    const u16* ga = Xb + (size_t)(row0 + wave*32 + lrow)*K + k0 + lcol;
    u16* la = As + wave*32*32;
    gl_lds(ga, la);
    gl_lds(ga + (size_t)16*K, la + 16*32);
    const u16* gw = Wb + (size_t)(col0 + wave*32 + lrow)*K + k0 + lcol;
    u16* lb = Bs + wave*32*32;
    gl_lds(gw, lb);
    gl_lds(gw + (size_t)16*K, lb + 16*32);
    __syncthreads();
    bf16x8 af[4], bfr[4];
    #pragma unroll
    for(int i=0;i<4;i++){
      af[i]  = *(const bf16x8*)&As[(wr + i*16 + m15)*32 + q*8];
      bfr[i] = *(const bf16x8*)&Bs[(wc + i*16 + m15)*32 + q*8];
    }
    #pragma unroll
    for(int i=0;i<4;i++)
      #pragma unroll
      for(int j=0;j<4;j++)
        acc[i][j] = __builtin_amdgcn_mfma_f32_16x16x32_bf16(af[i], bfr[j], acc[i][j], 0,0,0);
    __syncthreads();
  }
  #pragma unroll
  for(int j=0;j<4;j++){
    int cg = col0 + wc + j*16 + m15;
    float bias = Bb[cg];
    #pragma unroll
    for(int i=0;i<4;i++){
      int rbase = row0 + wr + i*16 + q*4;
      #pragma unroll
      for(int r=0;r<4;r++){
        float v = acc[i][j][r] + bias;
        if(ACT) v = gelu_f(v);
        Cb[(size_t)(rbase+r)*ldC + cg] = f2b(v);
      }
    }
  }
}

// ---------- final MFMA GEMM: out[:,0:115] = X2 @ Wbig + bias2, out[:,115]=bl ----------
__global__ __launch_bounds__(256) void k_fgemm(
    const u16* __restrict__ X2, const u16* __restrict__ WT, const float* __restrict__ bias2,
    const float* __restrict__ bl, float* __restrict__ out){
  __shared__ __align__(16) u16 As[128*32];
  __shared__ __align__(16) u16 Bs[128*32];
  int tid = threadIdx.x;
  int wave = tid>>6, lane = tid&63;
  int row0 = blockIdx.x*128;
  int wr = (wave>>1)*64, wc = (wave&1)*64;
  int lrow = lane>>2, lcol = (lane&3)*8, m15 = lane&15, q = lane>>4;
  f32x4 acc[4][4] = {};
  for(int k0=0;k0<2048;k0+=32){
    const u16* ga = X2 + (size_t)(row0 + wave*32 + lrow)*2048 + k0 + lcol;
    u16* la = As + wave*32*32;
    gl_lds(ga, la);
    gl_lds(ga + (size_t)16*2048, la + 16*32);
    const u16* gw = WT + (size_t)(wave*32 + lrow)*2048 + k0 + lcol;
    u16* lb = Bs + wave*32*32;
    gl_lds(gw, lb);
    gl_lds(gw + (size_t)16*2048, lb + 16*32);
    __syncthreads();
    bf16x8 af[4], bfr[4];
    #pragma unroll
    for(int i=0;i<4;i++){
      af[i]  = *(const bf16x8*)&As[(wr + i*16 + m15)*32 + q*8];
      bfr[i] = *(const bf16x8*)&Bs[(wc + i*16 + m15)*32 + q*8];
    }
    #pragma unroll
    for(int i=0;i<4;i++)
      #pragma unroll
      for(int j=0;j<4;j++)
        acc[i][j] = __builtin_amdgcn_mfma_f32_16x16x32_bf16(af[i], bfr[j], acc[i][j], 0,0,0);
    __syncthreads();
  }
  #pragma unroll
  for(int j=0;j<4;j++){
    int cg = wc + j*16 + m15;
    float bias = bias2[cg];
    #pragma unroll
    for(int i=0;i<4;i++){
      int rbase = row0 + wr + i*16 + q*4;
      #pragma unroll
      for(int r=0;r<4;r++){
        int rr = rbase + r;
        if(cg < 115) out[(size_t)rr*116 + cg] = acc[i][j][r] + bias;
        else if(cg == 115) out[(size_t)rr*116 + 115] = bl[rr];
      }
    }
  }
}

// ---------- K5: z = LN(h)*(1+gamma)+beta -> bf16 ----------
__global__ void k_z(const float* __restrict__ h, const float* __restrict__ hsum,
                    const float* __restrict__ hss, const float* __restrict__ g,
                    const float* __restrict__ bb, const u16* __restrict__ gb,
                    u16* __restrict__ z){
  int n = blockIdx.x, tid = threadIdx.x;
  float mu = hsum[n]*(1.0f/512.0f);
  float var = hss[n]*(1.0f/512.0f) - mu*mu;
  float rs = rsqrtf(var+1e-5f);
  for(int idx=tid; idx<512; idx+=256){
    float hv = h[(size_t)n*512+idx];
    float ln = (hv-mu)*rs*g[idx]+bb[idx];
    float gamma = b2f(gb[(size_t)n*1024+idx]);
    float beta  = b2f(gb[(size_t)n*1024+512+idx]);
    z[(size_t)n*512+idx] = f2b(ln*(1.0f+gamma)+beta);
  }
}

// ---------- score reduce: sc[k][n] = G[k][n,:] . w2[k] + b2[k] ----------
__global__ void k_scred(const u16* __restrict__ G, const float* __restrict__ w2,
                        const float* __restrict__ b2v, float* __restrict__ sc){
  int wave = threadIdx.x>>6, lane = threadIdx.x&63;
  int n = blockIdx.x*4 + wave;
  int k = blockIdx.y;
  uint2 gv = *(const uint2*)(G + ((size_t)k*NR + n)*256 + lane*4);
  float4 wv = *(const float4*)(w2 + k*256 + lane*4);
  float a0,a1,a2,a3;
  up2(gv.x,a0,a1); up2(gv.y,a2,a3);
  float s = a0*wv.x+a1*wv.y+a2*wv.z+a3*wv.w;
  s = wred(s);
  if(lane==0) sc[(size_t)k*NR+n] = s + b2v[k];
}

// ---------- K7: softmax over 10 + pooling -> P slots 0..3 (bf16) ----------
__global__ void k_pool(const u16* __restrict__ hb, const u16* __restrict__ z,
                       const float* __restrict__ sch, const float* __restrict__ scz,
                       u16* __restrict__ P){
  __shared__ float hl[10][512];
  int n = blockIdx.x, tid = threadIdx.x;
  int b = n>>12, t = n&4095;
  for(int idx=tid; idx<10*512; idx+=256){
    int row = idx>>9, d = idx&511;
    float v;
    if(row==0) v = b2f(z[(size_t)n*512+d]);
    else {
      int tc = t-4+(row-1); tc = tc<0?0:(tc>TT-1?TT-1:tc);
      v = b2f(hb[((size_t)(b<<12)+tc)*512+d]);
    }
    hl[row][d]=v;
  }
  __syncthreads();
  for(int k=0;k<4;k++){
    float s[10];
    s[0] = scz[(size_t)k*NR+n];
    #pragma unroll
    for(int j=0;j<9;j++){
      int tc = t-4+j; tc = tc<0?0:(tc>TT-1?TT-1:tc);
      s[j+1] = sch[(size_t)k*NR + (b<<12)+tc];
    }
    float m = s[0];
    #pragma unroll
    for(int j=1;j<10;j++) m = fmaxf(m,s[j]);
    float e[10], sum=0.f;
    #pragma unroll
    for(int j=0;j<10;j++){ e[j]=expf(s[j]-m); sum+=e[j]; }
    float inv = 1.0f/sum;
    for(int d=tid; d<512; d+=256){
      float v=0.f;
      #pragma unroll
      for(int r=0;r<10;r++) v += e[r]*hl[r][d];
      P[((size_t)k*NR + n)*512 + d] = f2b(v*inv);
    }
  }
}

// ---------- workspace layout (bytes) ----------
#define OFF_BL     0u
#define OFF_BSOFT  65536u
#define OFF_HSUM   131072u
#define OFF_HSS    196608u
#define OFF_SCH    262144u
#define OFF_SCZ    524288u
#define OFF_FIN    786432u            // bf16 NR*640 ; X2 (NR*2048 bf16) overlays fin+gb+z
#define OFF_GB     21757952u          // bf16 NR*1024
#define OFF_Z      55312384u          // bf16 NR*512
#define OFF_HBF    72089600u          // bf16 NR*512
#define OFF_WF     88866816u          // bf16 1024*640 (film_w^T)
#define OFF_WA     90177536u          // bf16 4*256*512 (attn_w1^T)
#define OFF_WP     91226112u          // bf16 4*512*512 (proj_w1^T)
#define OFF_P      93323264u          // bf16 4*NR*512 pooled (G aliases front 2 slots)
#define OFF_WB     160432128u         // bf16 128*2048 (Wbig^T)
#define OFF_B2     160956416u         // f32 128
// total 160,956,928 bytes (< R3's 177,209,344)

extern "C" void kernel_launch(void* const* d_in, const int* in_sizes, int n_in,
                              void* d_out, int out_size, void* d_ws, size_t ws_size,
                              hipStream_t stream){
  const float* h       = (const float*)d_in[0];
  const float* w_bnd   = (const float*)d_in[1];
  const float* b_bnd   = (const float*)d_in[2];
  const float* conv_k  = (const float*)d_in[3];
  const float* conv_b  = (const float*)d_in[4];
  const float* e0      = (const float*)d_in[5];
  const float* e1      = (const float*)d_in[6];
  const float* ln_in_g = (const float*)d_in[7];
  const float* ln_in_b = (const float*)d_in[8];
  const float* ln_h_g  = (const float*)d_in[9];
  const float* ln_h_b  = (const float*)d_in[10];
  const float* film_w  = (const float*)d_in[11];
  const float* film_b  = (const float*)d_in[12];
  const float* attn_w1 = (const float*)d_in[13];
  const float* attn_b1 = (const float*)d_in[14];
  const float* attn_w2 = (const float*)d_in[15];
  const float* attn_b2 = (const float*)d_in[16];
  const float* proj_w1 = (const float*)d_in[17];
  const float* proj_b1 = (const float*)d_in[18];
  const float* wq = (const float*)d_in[19];
  const float* bq = (const float*)d_in[20];
  const float* wr = (const float*)d_in[21];
  const float* br = (const float*)d_in[22];
  const float* wb_ = (const float*)d_in[23];
  const float* bb_ = (const float*)d_in[24];
  const float* wk = (const float*)d_in[25];
  const float* bk = (const float*)d_in[26];
  float* out = (float*)d_out;
  char* ws = (char*)d_ws;

  float* bl    = (float*)(ws + OFF_BL);
  float* bsoft = (float*)(ws + OFF_BSOFT);
  float* hsum  = (float*)(ws + OFF_HSUM);
  float* hss   = (float*)(ws + OFF_HSS);
  float* sch   = (float*)(ws + OFF_SCH);
  float* scz   = (float*)(ws + OFF_SCZ);
  u16* fin     = (u16*)(ws + OFF_FIN);
  u16* X2      = (u16*)(ws + OFF_FIN);   // overlays fin+gb+z (dead by proj1 time)
  u16* gb      = (u16*)(ws + OFF_GB);
  u16* z       = (u16*)(ws + OFF_Z);
  u16* hbf     = (u16*)(ws + OFF_HBF);
  u16* wfilm   = (u16*)(ws + OFF_WF);
  u16* wattn   = (u16*)(ws + OFF_WA);
  u16* wproj   = (u16*)(ws + OFF_WP);
  u16* P       = (u16*)(ws + OFF_P);
  u16* G       = P;   // alias: scores consumed (scred) before pool writes P slots
  u16* wbig    = (u16*)(ws + OFF_WB);
  float* bias2 = (float*)(ws + OFF_B2);

  // weight transpose-convert + h convert to bf16
  k_cvt<<<(NR*512)/1024,256,0,stream>>>(h, hbf, NR*512);
  {
    dim3 g(1024/32, 640/32, 1);
    k_tw<<<g,256,0,stream>>>(film_w, wfilm, 640, 1024, 0, 0);
  }
  {
    dim3 g(256/32, 512/32, 4);
    k_tw<<<g,256,0,stream>>>(attn_w1, wattn, 512, 256, 512LL*256, 256LL*512);
  }
  {
    dim3 g(512/32, 512/32, 4);
    k_tw<<<g,256,0,stream>>>(proj_w1, wproj, 512, 512, 512LL*512, 512LL*512);
  }
  k_wbig<<<128,256,0,stream>>>(wq,bq,wr,br,wb_,bb_,wk,bk, wbig, bias2);

  k_bnd<<<NR/4,256,0,stream>>>(h,w_bnd,b_bnd,bl,hsum,hss);
  k_conv<<<NR/256,256,0,stream>>>(bl,conv_k,conv_b,bsoft);
  k_filmin<<<NR,256,0,stream>>>(h,bsoft,e0,e1,ln_in_g,ln_in_b,fin);

  dim3 gFilm(1024/128, NR/128, 1);
  k_mgemm<0><<<gFilm,256,0,stream>>>(fin, wfilm, film_b, gb, 640, 1024, 1024, 0,0,0,0);

  k_z<<<NR,256,0,stream>>>(h,hsum,hss,ln_h_g,ln_h_b,gb,z);

  dim3 gSc(256/128, NR/128, 4);
  dim3 gRed(NR/4, 4);
  k_mgemm<1><<<gSc,256,0,stream>>>(hbf, wattn, attn_b1, G, 512, 256, 256,
                                   0, 256LL*512, 256, (long long)NR*256);
  k_scred<<<gRed,256,0,stream>>>(G, attn_w2, attn_b2, sch);
  k_mgemm<1><<<gSc,256,0,stream>>>(z, wattn, attn_b1, G, 512, 256, 256,
                                   0, 256LL*512, 256, (long long)NR*256);
  k_scred<<<gRed,256,0,stream>>>(G, attn_w2, attn_b2, scz);

  k_pool<<<NR,256,0,stream>>>(hbf,z,sch,scz,P);

  // proj1: all 4 heads batched, writes X2 column blocks (ld 2048)
  dim3 gP(512/128, NR/128, 4);
  k_mgemm<1><<<gP,256,0,stream>>>(P, wproj, proj_b1, X2, 512, 512, 2048,
                                  (long long)NR*512, 512LL*512, 512, 512);

  // final projection -> out f32
  k_fgemm<<<NR/128,256,0,stream>>>(X2, wbig, bias2, bl, out);
}

// Round 5
// 472.590 us; speedup vs baseline: 3.3740x; 1.1789x over previous
//
#include <hip/hip_runtime.h>
#include <hip/hip_bf16.h>

typedef unsigned short u16;
typedef unsigned int u32;

#define NR 16384   // B*T
#define TT 4096    // T

typedef __bf16 bf16_t;
typedef bf16_t bf16x8 __attribute__((ext_vector_type(8)));
typedef float f32x4 __attribute__((ext_vector_type(4)));

// ---------- bf16 helpers ----------
__device__ __forceinline__ float b2f(u16 u){ return __uint_as_float(((u32)u)<<16); }
__device__ __forceinline__ u16 f2b(float f){
  u32 u = __float_as_uint(f);
  u32 r = u + 0x7fffu + ((u>>16)&1u);
  return (u16)(r>>16);
}
__device__ __forceinline__ void up2(u32 u, float&a, float&b){
  a = __uint_as_float(u<<16);
  b = __uint_as_float(u & 0xffff0000u);
}
__device__ __forceinline__ void ld8(const u16* p, float* f){
  uint4 v = *(const uint4*)p;
  up2(v.x,f[0],f[1]); up2(v.y,f[2],f[3]);
  up2(v.z,f[4],f[5]); up2(v.w,f[6],f[7]);
}
__device__ __forceinline__ float wred(float v){
  #pragma unroll
  for(int o=32;o>0;o>>=1) v += __shfl_down(v,o,64);
  return v;
}
__device__ __forceinline__ float gelu_f(float x){
  return 0.5f*x*(1.0f+erff(x*0.7071067811865475f));
}
__device__ __forceinline__ void gl_lds(const void* g, void* l){
  __builtin_amdgcn_global_load_lds(
      (__attribute__((address_space(1))) void*)(void*)g,
      (__attribute__((address_space(3))) void*)l, 16, 0, 0);
}

// ---------- transpose-convert: src f32 [K][N] -> dst bf16 [N][K] ----------
__global__ void k_tw(const float* __restrict__ src, u16* __restrict__ dst,
                     int K, int N, long long sS, long long sD){
  __shared__ float t[32][33];
  const float* S = src + (size_t)blockIdx.z*sS;
  u16* D = dst + (size_t)blockIdx.z*sD;
  int k0 = blockIdx.y*32, n0 = blockIdx.x*32;
  int r = threadIdx.x>>5, c = threadIdx.x&31;
  #pragma unroll
  for(int p=0;p<4;p++) t[r+p*8][c] = S[(size_t)(k0+r+p*8)*N + n0 + c];
  __syncthreads();
  #pragma unroll
  for(int p=0;p<4;p++) D[(size_t)(n0+r+p*8)*K + k0 + c] = f2b(t[c][r+p*8]);
}

// ---------- build block-diagonal W2^T [128][2048] + bias2[128] ----------
__global__ void k_wbig(const float* __restrict__ wq, const float* __restrict__ bq,
                       const float* __restrict__ wr, const float* __restrict__ br,
                       const float* __restrict__ wb_, const float* __restrict__ bb_,
                       const float* __restrict__ wk, const float* __restrict__ bk,
                       u16* __restrict__ WT, float* __restrict__ bias2){
  int c = blockIdx.x, tid = threadIdx.x;
  const float* Wm=nullptr; const float* Bm=nullptr; int k=0,j=0,V=0;
  if(c<64){k=0;j=c;V=64;Wm=wq;Bm=bq;}
  else if(c<77){k=1;j=c-64;V=13;Wm=wr;Bm=br;}
  else if(c<90){k=2;j=c-77;V=13;Wm=wb_;Bm=bb_;}
  else if(c<115){k=3;j=c-90;V=25;Wm=wk;Bm=bk;}
  for(int kk=tid;kk<2048;kk+=256){
    float v = 0.f;
    if(c<115 && (kk>>9)==k) v = Wm[(size_t)(kk&511)*V + j];
    WT[(size_t)c*2048+kk] = f2b(v);
  }
  if(tid==0) bias2[c] = (c<115) ? Bm[j] : 0.f;
}

// ---------- K1: bl = h.w_bnd + b ; row stats of h ; h -> bf16 ----------
__global__ void k_bnd(const float* __restrict__ h, const float* __restrict__ wb,
                      const float* __restrict__ bb,
                      float* __restrict__ bl, float* __restrict__ hsum, float* __restrict__ hss,
                      u16* __restrict__ hbf){
  int wave = threadIdx.x>>6, lane = threadIdx.x&63;
  int n = blockIdx.x*4 + wave;
  const float4* hp = (const float4*)(h + (size_t)n*512 + lane*8);
  const float4* wp = (const float4*)(wb + lane*8);
  float4 h0 = hp[0], h1 = hp[1], w0 = wp[0], w1 = wp[1];
  float hv[8] = {h0.x,h0.y,h0.z,h0.w,h1.x,h1.y,h1.z,h1.w};
  float wv[8] = {w0.x,w0.y,w0.z,w0.w,w1.x,w1.y,w1.z,w1.w};
  float dot=0.f, s=0.f, ss=0.f;
  #pragma unroll
  for(int i=0;i<8;i++){ dot += hv[i]*wv[i]; s += hv[i]; ss += hv[i]*hv[i]; }
  u16* hd = hbf + (size_t)n*512 + lane*8;
  *(ushort4*)hd     = make_ushort4(f2b(hv[0]),f2b(hv[1]),f2b(hv[2]),f2b(hv[3]));
  *(ushort4*)(hd+4) = make_ushort4(f2b(hv[4]),f2b(hv[5]),f2b(hv[6]),f2b(hv[7]));
  dot = wred(dot); s = wred(s); ss = wred(ss);
  if(lane==0){ bl[n] = dot + bb[0]; hsum[n]=s; hss[n]=ss; }
}

// ---------- K2: conv9 (zero pad) + sigmoid ----------
__global__ void k_conv(const float* __restrict__ bl, const float* __restrict__ ck,
                       const float* __restrict__ cb, float* __restrict__ bsoft){
  int n = blockIdx.x*256 + threadIdx.x;
  int b = n>>12, t = n&4095;
  float acc = cb[0];
  #pragma unroll
  for(int i=0;i<9;i++){
    int tt = t-4+i;
    if(tt>=0 && tt<TT) acc += bl[(b<<12)+tt]*ck[i];
  }
  bsoft[n] = 1.0f/(1.0f+expf(-acc));
}

// ---------- K3: film_in = LN(concat(h, eb)) -> bf16 ----------
__global__ void k_filmin(const float* __restrict__ h, const float* __restrict__ bsoft,
                         const float* __restrict__ e0, const float* __restrict__ e1,
                         const float* __restrict__ g, const float* __restrict__ bb,
                         u16* __restrict__ fin){
  __shared__ float xb[640];
  __shared__ float red[8];
  int n = blockIdx.x, tid = threadIdx.x;
  float bs = bsoft[n];
  float s=0.f, ss=0.f;
  for(int idx=tid; idx<640; idx+=256){
    float v;
    if(idx<512) v = h[(size_t)n*512+idx];
    else { int j=idx-512; v = bs*e1[j] + (1.0f-bs)*e0[j]; }
    xb[idx]=v; s+=v; ss+=v*v;
  }
  s = wred(s); ss = wred(ss);
  int wave = tid>>6, lane = tid&63;
  if(lane==0){ red[wave]=s; red[wave+4]=ss; }
  __syncthreads();
  float S = red[0]+red[1]+red[2]+red[3];
  float SS = red[4]+red[5]+red[6]+red[7];
  float mu = S*(1.0f/640.0f);
  float var = SS*(1.0f/640.0f) - mu*mu;
  float rs = rsqrtf(var + 1e-5f);
  for(int idx=tid; idx<640; idx+=256){
    float v = (xb[idx]-mu)*rs*g[idx] + bb[idx];
    fin[(size_t)n*640+idx] = f2b(v);
  }
}

// ---------- MFMA GEMM: C = act(X @ W + bias) ----------
template<int ACT>
__global__ __launch_bounds__(256) void k_mgemm(
    const u16* __restrict__ X, const u16* __restrict__ WT, const float* __restrict__ Bv,
    u16* __restrict__ C, int K, int Nc, int ldC,
    long long sX, long long sW, long long sB, long long sC){
  __shared__ __align__(16) u16 As[128*32];
  __shared__ __align__(16) u16 Bs[128*32];
  int tid = threadIdx.x;
  int wave = tid>>6, lane = tid&63;
  const u16* Xb = X + (size_t)blockIdx.z*sX;
  const u16* Wb = WT + (size_t)blockIdx.z*sW;
  const float* Bb = Bv + (size_t)blockIdx.z*sB;
  u16* Cb = C + (size_t)blockIdx.z*sC;
  int row0 = blockIdx.y*128, col0 = blockIdx.x*128;
  int wr = (wave>>1)*64, wc = (wave&1)*64;
  int lrow = lane>>2;
  int lcol = (lane&3)*8;
  int m15 = lane&15, q = lane>>4;
  f32x4 acc[4][4] = {};
  for(int k0=0;k0<K;k0+=32){
    const u16* ga = Xb + (size_t)(row0 + wave*32 + lrow)*K + k0 + lcol;
    u16* la = As + wave*32*32;
    gl_lds(ga, la);
    gl_lds(ga + (size_t)16*K, la + 16*32);
    const u16* gw = Wb + (size_t)(col0 + wave*32 + lrow)*K + k0 + lcol;
    u16* lb = Bs + wave*32*32;
    gl_lds(gw, lb);
    gl_lds(gw + (size_t)16*K, lb + 16*32);
    __syncthreads();
    bf16x8 af[4], bfr[4];
    #pragma unroll
    for(int i=0;i<4;i++){
      af[i]  = *(const bf16x8*)&As[(wr + i*16 + m15)*32 + q*8];
      bfr[i] = *(const bf16x8*)&Bs[(wc + i*16 + m15)*32 + q*8];
    }
    #pragma unroll
    for(int i=0;i<4;i++)
      #pragma unroll
      for(int j=0;j<4;j++)
        acc[i][j] = __builtin_amdgcn_mfma_f32_16x16x32_bf16(af[i], bfr[j], acc[i][j], 0,0,0);
    __syncthreads();
  }
  #pragma unroll
  for(int j=0;j<4;j++){
    int cg = col0 + wc + j*16 + m15;
    float bias = Bb[cg];
    #pragma unroll
    for(int i=0;i<4;i++){
      int rbase = row0 + wr + i*16 + q*4;
      #pragma unroll
      for(int r=0;r<4;r++){
        float v = acc[i][j][r] + bias;
        if(ACT) v = gelu_f(v);
        Cb[(size_t)(rbase+r)*ldC + cg] = f2b(v);
      }
    }
  }
}

// ---------- final MFMA GEMM: out[:,0:115] = X2 @ Wbig + bias2, out[:,115]=bl ----------
__global__ __launch_bounds__(256) void k_fgemm(
    const u16* __restrict__ X2, const u16* __restrict__ WT, const float* __restrict__ bias2,
    const float* __restrict__ bl, float* __restrict__ out){
  __shared__ __align__(16) u16 As[128*32];
  __shared__ __align__(16) u16 Bs[128*32];
  int tid = threadIdx.x;
  int wave = tid>>6, lane = tid&63;
  int row0 = blockIdx.x*128;
  int wr = (wave>>1)*64, wc = (wave&1)*64;
  int lrow = lane>>2, lcol = (lane&3)*8, m15 = lane&15, q = lane>>4;
  f32x4 acc[4][4] = {};
  for(int k0=0;k0<2048;k0+=32){
    const u16* ga = X2 + (size_t)(row0 + wave*32 + lrow)*2048 + k0 + lcol;
    u16* la = As + wave*32*32;
    gl_lds(ga, la);
    gl_lds(ga + (size_t)16*2048, la + 16*32);
    const u16* gw = WT + (size_t)(wave*32 + lrow)*2048 + k0 + lcol;
    u16* lb = Bs + wave*32*32;
    gl_lds(gw, lb);
    gl_lds(gw + (size_t)16*2048, lb + 16*32);
    __syncthreads();
    bf16x8 af[4], bfr[4];
    #pragma unroll
    for(int i=0;i<4;i++){
      af[i]  = *(const bf16x8*)&As[(wr + i*16 + m15)*32 + q*8];
      bfr[i] = *(const bf16x8*)&Bs[(wc + i*16 + m15)*32 + q*8];
    }
    #pragma unroll
    for(int i=0;i<4;i++)
      #pragma unroll
      for(int j=0;j<4;j++)
        acc[i][j] = __builtin_amdgcn_mfma_f32_16x16x32_bf16(af[i], bfr[j], acc[i][j], 0,0,0);
    __syncthreads();
  }
  #pragma unroll
  for(int j=0;j<4;j++){
    int cg = wc + j*16 + m15;
    float bias = bias2[cg];
    #pragma unroll
    for(int i=0;i<4;i++){
      int rbase = row0 + wr + i*16 + q*4;
      #pragma unroll
      for(int r=0;r<4;r++){
        int rr = rbase + r;
        if(cg < 115) out[(size_t)rr*116 + cg] = acc[i][j][r] + bias;
        else if(cg == 115) out[(size_t)rr*116 + 115] = bl[rr];
      }
    }
  }
}

// ---------- K5: z = LN(h)*(1+gamma)+beta -> bf16 ----------
__global__ void k_z(const float* __restrict__ h, const float* __restrict__ hsum,
                    const float* __restrict__ hss, const float* __restrict__ g,
                    const float* __restrict__ bb, const u16* __restrict__ gb,
                    u16* __restrict__ z){
  int n = blockIdx.x, tid = threadIdx.x;
  float mu = hsum[n]*(1.0f/512.0f);
  float var = hss[n]*(1.0f/512.0f) - mu*mu;
  float rs = rsqrtf(var+1e-5f);
  for(int idx=tid; idx<512; idx+=256){
    float hv = h[(size_t)n*512+idx];
    float ln = (hv-mu)*rs*g[idx]+bb[idx];
    float gamma = b2f(gb[(size_t)n*1024+idx]);
    float beta  = b2f(gb[(size_t)n*1024+512+idx]);
    z[(size_t)n*512+idx] = f2b(ln*(1.0f+gamma)+beta);
  }
}

// ---------- score reduce: sc[k][n] = G[k][n,:] . w2[k] + b2[k] ----------
__global__ void k_scred(const u16* __restrict__ G, const float* __restrict__ w2,
                        const float* __restrict__ b2v, float* __restrict__ sc){
  int wave = threadIdx.x>>6, lane = threadIdx.x&63;
  int n = blockIdx.x*4 + wave;
  int k = blockIdx.y;
  uint2 gv = *(const uint2*)(G + ((size_t)k*NR + n)*256 + lane*4);
  float4 wv = *(const float4*)(w2 + k*256 + lane*4);
  float a0,a1,a2,a3;
  up2(gv.x,a0,a1); up2(gv.y,a2,a3);
  float s = a0*wv.x+a1*wv.y+a2*wv.z+a3*wv.w;
  s = wred(s);
  if(lane==0) sc[(size_t)k*NR+n] = s + b2v[k];
}

// ---------- K7: one wave per row: lane-parallel softmax + register pooling ----------
__global__ __launch_bounds__(256) void k_pool(
    const u16* __restrict__ hb, const u16* __restrict__ z,
    const float* __restrict__ sch, const float* __restrict__ scz,
    u16* __restrict__ P){
  int wave = threadIdx.x>>6, lane = threadIdx.x&63;
  int n = blockIdx.x*4 + wave;
  int b = n>>12, t = n&4095;
  // lane = j*4+k : score slot j (0=z, 1..9=h offsets), head k; j>=10 padded
  int k = lane&3, j = lane>>2;
  float s;
  if(j==0) s = scz[(size_t)k*NR+n];
  else if(j<10){
    int tc = t-5+j; tc = tc<0?0:(tc>TT-1?TT-1:tc);
    s = sch[(size_t)k*NR + (b<<12) + tc];
  } else s = -1e30f;
  float m = s;
  #pragma unroll
  for(int o=4;o<64;o<<=1) m = fmaxf(m, __shfl_xor(m,o,64));
  float e = (j<10)? expf(s-m) : 0.f;
  float sum = e;
  #pragma unroll
  for(int o=4;o<64;o<<=1) sum += __shfl_xor(sum,o,64);
  float ev = e/sum;
  // pooling: lane owns 8 contiguous d
  int d0 = lane*8;
  float acc[4][8] = {};
  #pragma unroll
  for(int jj=0;jj<10;jj++){
    const u16* src;
    if(jj==0) src = z + (size_t)n*512 + d0;
    else {
      int tc = t-5+jj; tc = tc<0?0:(tc>TT-1?TT-1:tc);
      src = hb + ((size_t)(b<<12)+tc)*512 + d0;
    }
    float f[8]; ld8(src, f);
    float w0 = __shfl(ev, jj*4+0, 64);
    float w1 = __shfl(ev, jj*4+1, 64);
    float w2 = __shfl(ev, jj*4+2, 64);
    float w3 = __shfl(ev, jj*4+3, 64);
    #pragma unroll
    for(int i=0;i<8;i++){
      acc[0][i] += w0*f[i];
      acc[1][i] += w1*f[i];
      acc[2][i] += w2*f[i];
      acc[3][i] += w3*f[i];
    }
  }
  #pragma unroll
  for(int kk=0;kk<4;kk++){
    u16* dst = P + ((size_t)kk*NR + n)*512 + d0;
    *(ushort4*)dst     = make_ushort4(f2b(acc[kk][0]),f2b(acc[kk][1]),f2b(acc[kk][2]),f2b(acc[kk][3]));
    *(ushort4*)(dst+4) = make_ushort4(f2b(acc[kk][4]),f2b(acc[kk][5]),f2b(acc[kk][6]),f2b(acc[kk][7]));
  }
}

// ---------- workspace layout (bytes) ----------
#define OFF_BL     0u
#define OFF_BSOFT  65536u
#define OFF_HSUM   131072u
#define OFF_HSS    196608u
#define OFF_SCH    262144u
#define OFF_SCZ    524288u
#define OFF_FIN    786432u            // bf16 NR*640 ; X2 (NR*2048 bf16) overlays fin+gb+z
#define OFF_GB     21757952u          // bf16 NR*1024
#define OFF_Z      55312384u          // bf16 NR*512
#define OFF_HBF    72089600u          // bf16 NR*512
#define OFF_WF     88866816u          // bf16 1024*640 (film_w^T)
#define OFF_WA     90177536u          // bf16 4*256*512 (attn_w1^T)
#define OFF_WP     91226112u          // bf16 4*512*512 (proj_w1^T)
#define OFF_P      93323264u          // bf16 4*NR*512 pooled (G aliases front 2 slots)
#define OFF_WB     160432128u         // bf16 128*2048 (Wbig^T)
#define OFF_B2     160956416u         // f32 128

extern "C" void kernel_launch(void* const* d_in, const int* in_sizes, int n_in,
                              void* d_out, int out_size, void* d_ws, size_t ws_size,
                              hipStream_t stream){
  const float* h       = (const float*)d_in[0];
  const float* w_bnd   = (const float*)d_in[1];
  const float* b_bnd   = (const float*)d_in[2];
  const float* conv_k  = (const float*)d_in[3];
  const float* conv_b  = (const float*)d_in[4];
  const float* e0      = (const float*)d_in[5];
  const float* e1      = (const float*)d_in[6];
  const float* ln_in_g = (const float*)d_in[7];
  const float* ln_in_b = (const float*)d_in[8];
  const float* ln_h_g  = (const float*)d_in[9];
  const float* ln_h_b  = (const float*)d_in[10];
  const float* film_w  = (const float*)d_in[11];
  const float* film_b  = (const float*)d_in[12];
  const float* attn_w1 = (const float*)d_in[13];
  const float* attn_b1 = (const float*)d_in[14];
  const float* attn_w2 = (const float*)d_in[15];
  const float* attn_b2 = (const float*)d_in[16];
  const float* proj_w1 = (const float*)d_in[17];
  const float* proj_b1 = (const float*)d_in[18];
  const float* wq = (const float*)d_in[19];
  const float* bq = (const float*)d_in[20];
  const float* wr = (const float*)d_in[21];
  const float* br = (const float*)d_in[22];
  const float* wb_ = (const float*)d_in[23];
  const float* bb_ = (const float*)d_in[24];
  const float* wk = (const float*)d_in[25];
  const float* bk = (const float*)d_in[26];
  float* out = (float*)d_out;
  char* ws = (char*)d_ws;

  float* bl    = (float*)(ws + OFF_BL);
  float* bsoft = (float*)(ws + OFF_BSOFT);
  float* hsum  = (float*)(ws + OFF_HSUM);
  float* hss   = (float*)(ws + OFF_HSS);
  float* sch   = (float*)(ws + OFF_SCH);
  float* scz   = (float*)(ws + OFF_SCZ);
  u16* fin     = (u16*)(ws + OFF_FIN);
  u16* X2      = (u16*)(ws + OFF_FIN);   // overlays fin+gb+z (dead by proj1 time)
  u16* gb      = (u16*)(ws + OFF_GB);
  u16* z       = (u16*)(ws + OFF_Z);
  u16* hbf     = (u16*)(ws + OFF_HBF);
  u16* wfilm   = (u16*)(ws + OFF_WF);
  u16* wattn   = (u16*)(ws + OFF_WA);
  u16* wproj   = (u16*)(ws + OFF_WP);
  u16* P       = (u16*)(ws + OFF_P);
  u16* G       = P;   // alias: scores consumed (scred) before pool writes P slots
  u16* wbig    = (u16*)(ws + OFF_WB);
  float* bias2 = (float*)(ws + OFF_B2);

  // weight transpose-convert
  {
    dim3 g(1024/32, 640/32, 1);
    k_tw<<<g,256,0,stream>>>(film_w, wfilm, 640, 1024, 0, 0);
  }
  {
    dim3 g(256/32, 512/32, 4);
    k_tw<<<g,256,0,stream>>>(attn_w1, wattn, 512, 256, 512LL*256, 256LL*512);
  }
  {
    dim3 g(512/32, 512/32, 4);
    k_tw<<<g,256,0,stream>>>(proj_w1, wproj, 512, 512, 512LL*512, 512LL*512);
  }
  k_wbig<<<128,256,0,stream>>>(wq,bq,wr,br,wb_,bb_,wk,bk, wbig, bias2);

  k_bnd<<<NR/4,256,0,stream>>>(h,w_bnd,b_bnd,bl,hsum,hss,hbf);
  k_conv<<<NR/256,256,0,stream>>>(bl,conv_k,conv_b,bsoft);
  k_filmin<<<NR,256,0,stream>>>(h,bsoft,e0,e1,ln_in_g,ln_in_b,fin);

  dim3 gFilm(1024/128, NR/128, 1);
  k_mgemm<0><<<gFilm,256,0,stream>>>(fin, wfilm, film_b, gb, 640, 1024, 1024, 0,0,0,0);

  k_z<<<NR,256,0,stream>>>(h,hsum,hss,ln_h_g,ln_h_b,gb,z);

  dim3 gSc(256/128, NR/128, 4);
  dim3 gRed(NR/4, 4);
  k_mgemm<1><<<gSc,256,0,stream>>>(hbf, wattn, attn_b1, G, 512, 256, 256,
                                   0, 256LL*512, 256, (long long)NR*256);
  k_scred<<<gRed,256,0,stream>>>(G, attn_w2, attn_b2, sch);
  k_mgemm<1><<<gSc,256,0,stream>>>(z, wattn, attn_b1, G, 512, 256, 256,
                                   0, 256LL*512, 256, (long long)NR*256);
  k_scred<<<gRed,256,0,stream>>>(G, attn_w2, attn_b2, scz);

  k_pool<<<NR/4,256,0,stream>>>(hbf,z,sch,scz,P);

  // proj1: all 4 heads batched, writes X2 column blocks (ld 2048)
  dim3 gP(512/128, NR/128, 4);
  k_mgemm<1><<<gP,256,0,stream>>>(P, wproj, proj_b1, X2, 512, 512, 2048,
                                  (long long)NR*512, 512LL*512, 512, 512);

  // final projection -> out f32
  k_fgemm<<<NR/128,256,0,stream>>>(X2, wbig, bias2, bl, out);
}

// Round 6
// 444.552 us; speedup vs baseline: 3.5868x; 1.0631x over previous
//
#include <hip/hip_runtime.h>
#include <hip/hip_bf16.h>

typedef unsigned short u16;
typedef unsigned int u32;

#define NR 16384   // B*T
#define TT 4096    // T

typedef __bf16 bf16_t;
typedef bf16_t bf16x8 __attribute__((ext_vector_type(8)));
typedef float f32x4 __attribute__((ext_vector_type(4)));

// ---------- bf16 helpers ----------
__device__ __forceinline__ float b2f(u16 u){ return __uint_as_float(((u32)u)<<16); }
__device__ __forceinline__ u16 f2b(float f){
  u32 u = __float_as_uint(f);
  u32 r = u + 0x7fffu + ((u>>16)&1u);
  return (u16)(r>>16);
}
__device__ __forceinline__ void up2(u32 u, float&a, float&b){
  a = __uint_as_float(u<<16);
  b = __uint_as_float(u & 0xffff0000u);
}
__device__ __forceinline__ void ld8(const u16* p, float* f){
  uint4 v = *(const uint4*)p;
  up2(v.x,f[0],f[1]); up2(v.y,f[2],f[3]);
  up2(v.z,f[4],f[5]); up2(v.w,f[6],f[7]);
}
__device__ __forceinline__ float wred(float v){
  #pragma unroll
  for(int o=32;o>0;o>>=1) v += __shfl_down(v,o,64);
  return v;
}
__device__ __forceinline__ float gelu_f(float x){
  return 0.5f*x*(1.0f+erff(x*0.7071067811865475f));
}
__device__ __forceinline__ void gl_lds(const void* g, void* l){
  __builtin_amdgcn_global_load_lds(
      (__attribute__((address_space(1))) void*)(void*)g,
      (__attribute__((address_space(3))) void*)l, 16, 0, 0);
}

// ---------- transpose-convert: src f32 [K][N] -> dst bf16 [N][K] ----------
__global__ void k_tw(const float* __restrict__ src, u16* __restrict__ dst,
                     int K, int N, long long sS, long long sD){
  __shared__ float t[32][33];
  const float* S = src + (size_t)blockIdx.z*sS;
  u16* D = dst + (size_t)blockIdx.z*sD;
  int k0 = blockIdx.y*32, n0 = blockIdx.x*32;
  int r = threadIdx.x>>5, c = threadIdx.x&31;
  #pragma unroll
  for(int p=0;p<4;p++) t[r+p*8][c] = S[(size_t)(k0+r+p*8)*N + n0 + c];
  __syncthreads();
  #pragma unroll
  for(int p=0;p<4;p++) D[(size_t)(n0+r+p*8)*K + k0 + c] = f2b(t[c][r+p*8]);
}

// ---------- build compact W2^T [5][32][512] + bias [5*32] (pseudo-heads) ----------
__global__ void k_w2c(const float* __restrict__ wq, const float* __restrict__ bq,
                      const float* __restrict__ wr, const float* __restrict__ br,
                      const float* __restrict__ wb_, const float* __restrict__ bb_,
                      const float* __restrict__ wk, const float* __restrict__ bk,
                      u16* __restrict__ W2c, float* __restrict__ b2c){
  int idx = blockIdx.x;            // 0..159 : p*32 + j
  int p = idx>>5, j = idx&31, tid = threadIdx.x;
  const float* Wm; const float* Bm; int V; int cofs = 0;
  if(p<=1){ Wm=wq; Bm=bq; V=64; cofs = p*32; }
  else if(p==2){ Wm=wr; Bm=br; V=13; }
  else if(p==3){ Wm=wb_; Bm=bb_; V=13; }
  else { Wm=wk; Bm=bk; V=25; }
  int c = j + cofs;
  bool valid = c < V;
  for(int k=tid;k<512;k+=256)
    W2c[(size_t)idx*512 + k] = f2b(valid ? Wm[(size_t)k*V + c] : 0.f);
  if(tid==0) b2c[idx] = valid ? Bm[c] : 0.f;
}

// ---------- K1: bl = h.w_bnd + b ; row stats ; h->bf16 ; out[:,115]=bl ----------
__global__ void k_bnd(const float* __restrict__ h, const float* __restrict__ wb,
                      const float* __restrict__ bb,
                      float* __restrict__ bl, float* __restrict__ hsum, float* __restrict__ hss,
                      u16* __restrict__ hbf, float* __restrict__ out){
  int wave = threadIdx.x>>6, lane = threadIdx.x&63;
  int n = blockIdx.x*4 + wave;
  const float4* hp = (const float4*)(h + (size_t)n*512 + lane*8);
  const float4* wp = (const float4*)(wb + lane*8);
  float4 h0 = hp[0], h1 = hp[1], w0 = wp[0], w1 = wp[1];
  float hv[8] = {h0.x,h0.y,h0.z,h0.w,h1.x,h1.y,h1.z,h1.w};
  float wv[8] = {w0.x,w0.y,w0.z,w0.w,w1.x,w1.y,w1.z,w1.w};
  float dot=0.f, s=0.f, ss=0.f;
  #pragma unroll
  for(int i=0;i<8;i++){ dot += hv[i]*wv[i]; s += hv[i]; ss += hv[i]*hv[i]; }
  u16* hd = hbf + (size_t)n*512 + lane*8;
  *(ushort4*)hd     = make_ushort4(f2b(hv[0]),f2b(hv[1]),f2b(hv[2]),f2b(hv[3]));
  *(ushort4*)(hd+4) = make_ushort4(f2b(hv[4]),f2b(hv[5]),f2b(hv[6]),f2b(hv[7]));
  dot = wred(dot); s = wred(s); ss = wred(ss);
  if(lane==0){
    float v = dot + bb[0];
    bl[n] = v; hsum[n]=s; hss[n]=ss;
    out[(size_t)n*116 + 115] = v;
  }
}

// ---------- K2: conv9 (zero pad) + sigmoid ----------
__global__ void k_conv(const float* __restrict__ bl, const float* __restrict__ ck,
                       const float* __restrict__ cb, float* __restrict__ bsoft){
  int n = blockIdx.x*256 + threadIdx.x;
  int b = n>>12, t = n&4095;
  float acc = cb[0];
  #pragma unroll
  for(int i=0;i<9;i++){
    int tt = t-4+i;
    if(tt>=0 && tt<TT) acc += bl[(b<<12)+tt]*ck[i];
  }
  bsoft[n] = 1.0f/(1.0f+expf(-acc));
}

// ---------- K3: film_in = LN(concat(h, eb)) -> bf16 ----------
__global__ void k_filmin(const float* __restrict__ h, const float* __restrict__ bsoft,
                         const float* __restrict__ e0, const float* __restrict__ e1,
                         const float* __restrict__ g, const float* __restrict__ bb,
                         u16* __restrict__ fin){
  __shared__ float xb[640];
  __shared__ float red[8];
  int n = blockIdx.x, tid = threadIdx.x;
  float bs = bsoft[n];
  float s=0.f, ss=0.f;
  for(int idx=tid; idx<640; idx+=256){
    float v;
    if(idx<512) v = h[(size_t)n*512+idx];
    else { int j=idx-512; v = bs*e1[j] + (1.0f-bs)*e0[j]; }
    xb[idx]=v; s+=v; ss+=v*v;
  }
  s = wred(s); ss = wred(ss);
  int wave = tid>>6, lane = tid&63;
  if(lane==0){ red[wave]=s; red[wave+4]=ss; }
  __syncthreads();
  float S = red[0]+red[1]+red[2]+red[3];
  float SS = red[4]+red[5]+red[6]+red[7];
  float mu = S*(1.0f/640.0f);
  float var = SS*(1.0f/640.0f) - mu*mu;
  float rs = rsqrtf(var + 1e-5f);
  for(int idx=tid; idx<640; idx+=256){
    float v = (xb[idx]-mu)*rs*g[idx] + bb[idx];
    fin[(size_t)n*640+idx] = f2b(v);
  }
}

// ---------- MFMA GEMM: C = act(X @ W + bias) ----------
// Operand-swapped MFMA: D.row=n (B), D.col=m (A) -> lane holds 4 consecutive cols
// of one row -> ushort4 stores + float4 bias loads.
template<int ACT>
__global__ __launch_bounds__(256) void k_mgemm(
    const u16* __restrict__ X, const u16* __restrict__ WT, const float* __restrict__ Bv,
    u16* __restrict__ C, int K, int Nc, int ldC,
    long long sX, long long sW, long long sB, long long sC){
  __shared__ __align__(16) u16 As[128*32];
  __shared__ __align__(16) u16 Bs[128*32];
  int tid = threadIdx.x;
  int wave = tid>>6, lane = tid&63;
  const u16* Xb = X + (size_t)blockIdx.z*sX;
  const u16* Wb = WT + (size_t)blockIdx.z*sW;
  const float* Bb = Bv + (size_t)blockIdx.z*sB;
  u16* Cb = C + (size_t)blockIdx.z*sC;
  int row0 = blockIdx.y*128, col0 = blockIdx.x*128;
  int wr = (wave>>1)*64, wc = (wave&1)*64;
  int lrow = lane>>2;
  int lcol = (lane&3)*8;
  int m15 = lane&15, q = lane>>4;
  f32x4 acc[4][4] = {};
  for(int k0=0;k0<K;k0+=32){
    const u16* ga = Xb + (size_t)(row0 + wave*32 + lrow)*K + k0 + lcol;
    u16* la = As + wave*32*32;
    gl_lds(ga, la);
    gl_lds(ga + (size_t)16*K, la + 16*32);
    const u16* gw = Wb + (size_t)(col0 + wave*32 + lrow)*K + k0 + lcol;
    u16* lb = Bs + wave*32*32;
    gl_lds(gw, lb);
    gl_lds(gw + (size_t)16*K, lb + 16*32);
    __syncthreads();
    bf16x8 af[4], bfr[4];
    #pragma unroll
    for(int i=0;i<4;i++){
      af[i]  = *(const bf16x8*)&As[(wr + i*16 + m15)*32 + q*8];
      bfr[i] = *(const bf16x8*)&Bs[(wc + i*16 + m15)*32 + q*8];
    }
    #pragma unroll
    for(int i=0;i<4;i++)
      #pragma unroll
      for(int j=0;j<4;j++)
        acc[i][j] = __builtin_amdgcn_mfma_f32_16x16x32_bf16(bfr[j], af[i], acc[i][j], 0,0,0);
    __syncthreads();
  }
  // acc[i][j][r] = C[m = row0+wr+i*16+m15][n = col0+wc+j*16+q*4+r]
  #pragma unroll
  for(int i=0;i<4;i++){
    size_t mrow = (size_t)(row0 + wr + i*16 + m15)*ldC;
    #pragma unroll
    for(int j=0;j<4;j++){
      int n0 = col0 + wc + j*16 + q*4;
      float4 bias = *(const float4*)&Bb[n0];
      float v0 = acc[i][j][0] + bias.x;
      float v1 = acc[i][j][1] + bias.y;
      float v2 = acc[i][j][2] + bias.z;
      float v3 = acc[i][j][3] + bias.w;
      if(ACT){ v0=gelu_f(v0); v1=gelu_f(v1); v2=gelu_f(v2); v3=gelu_f(v3); }
      *(ushort4*)(Cb + mrow + n0) = make_ushort4(f2b(v0),f2b(v1),f2b(v2),f2b(v3));
    }
  }
}

// ---------- final compact GEMM: out cols per pseudo-head ----------
// X2 rows x (head K-slice 512) @ W2c[p] (32 x 512) -> out[:, B0[p]..B0[p]+V)
__global__ __launch_bounds__(256) void k_f2(
    const u16* __restrict__ X2, const u16* __restrict__ W2c, const float* __restrict__ b2c,
    float* __restrict__ out){
  __shared__ __align__(16) u16 As[128*32];
  __shared__ __align__(16) u16 Bs[32*32];
  int tid = threadIdx.x, wave = tid>>6, lane = tid&63;
  int row0 = blockIdx.x*128, p = blockIdx.y;
  int hk = (p<=1)?0:(p-1);                // head index 0..3
  int B0 = (p==0)?0:(p==1)?32:(p==2)?64:(p==3)?77:90;
  int V  = (p<=1)?32:(p==4)?25:13;
  int lrow = lane>>2, lcol = (lane&3)*8, m15 = lane&15, q = lane>>4;
  f32x4 acc[2][2] = {};
  for(int k0=0;k0<512;k0+=32){
    const u16* ga = X2 + (size_t)(row0 + wave*32 + lrow)*2048 + hk*512 + k0 + lcol;
    u16* la = As + wave*32*32;
    gl_lds(ga, la);
    gl_lds(ga + (size_t)16*2048, la + 16*32);
    if(wave<2){
      const u16* gw = W2c + (size_t)(p*32 + wave*16 + lrow)*512 + k0 + lcol;
      gl_lds(gw, Bs + wave*16*32);
    }
    __syncthreads();
    bf16x8 af[2], bfr[2];
    #pragma unroll
    for(int i=0;i<2;i++) af[i] = *(const bf16x8*)&As[(wave*32 + i*16 + m15)*32 + q*8];
    #pragma unroll
    for(int j=0;j<2;j++) bfr[j] = *(const bf16x8*)&Bs[(j*16+m15)*32 + q*8];
    #pragma unroll
    for(int i=0;i<2;i++)
      #pragma unroll
      for(int j=0;j<2;j++)
        acc[i][j] = __builtin_amdgcn_mfma_f32_16x16x32_bf16(bfr[j], af[i], acc[i][j], 0,0,0);
    __syncthreads();
  }
  #pragma unroll
  for(int i=0;i<2;i++){
    size_t mrow = (size_t)(row0 + wave*32 + i*16 + m15)*116;
    #pragma unroll
    for(int j=0;j<2;j++){
      int nl0 = j*16 + q*4;
      #pragma unroll
      for(int r=0;r<4;r++){
        int nl = nl0 + r;
        if(nl < V) out[mrow + B0 + nl] = acc[i][j][r] + b2c[p*32+nl];
      }
    }
  }
}

// ---------- K5: z = LN(h)*(1+gamma)+beta -> bf16 ----------
__global__ void k_z(const float* __restrict__ h, const float* __restrict__ hsum,
                    const float* __restrict__ hss, const float* __restrict__ g,
                    const float* __restrict__ bb, const u16* __restrict__ gb,
                    u16* __restrict__ z){
  int n = blockIdx.x, tid = threadIdx.x;
  float mu = hsum[n]*(1.0f/512.0f);
  float var = hss[n]*(1.0f/512.0f) - mu*mu;
  float rs = rsqrtf(var+1e-5f);
  for(int idx=tid; idx<512; idx+=256){
    float hv = h[(size_t)n*512+idx];
    float ln = (hv-mu)*rs*g[idx]+bb[idx];
    float gamma = b2f(gb[(size_t)n*1024+idx]);
    float beta  = b2f(gb[(size_t)n*1024+512+idx]);
    z[(size_t)n*512+idx] = f2b(ln*(1.0f+gamma)+beta);
  }
}

// ---------- score reduce: sc[k][n] = G[k][n,:] . w2[k] + b2[k] ----------
__global__ void k_scred(const u16* __restrict__ G, const float* __restrict__ w2,
                        const float* __restrict__ b2v, float* __restrict__ sc){
  int wave = threadIdx.x>>6, lane = threadIdx.x&63;
  int n = blockIdx.x*4 + wave;
  int k = blockIdx.y;
  uint2 gv = *(const uint2*)(G + ((size_t)k*NR + n)*256 + lane*4);
  float4 wv = *(const float4*)(w2 + k*256 + lane*4);
  float a0,a1,a2,a3;
  up2(gv.x,a0,a1); up2(gv.y,a2,a3);
  float s = a0*wv.x+a1*wv.y+a2*wv.z+a3*wv.w;
  s = wred(s);
  if(lane==0) sc[(size_t)k*NR+n] = s + b2v[k];
}

// ---------- K7: one wave per row: lane-parallel softmax + register pooling ----------
__global__ __launch_bounds__(256) void k_pool(
    const u16* __restrict__ hb, const u16* __restrict__ z,
    const float* __restrict__ sch, const float* __restrict__ scz,
    u16* __restrict__ P){
  int wave = threadIdx.x>>6, lane = threadIdx.x&63;
  int n = blockIdx.x*4 + wave;
  int b = n>>12, t = n&4095;
  int k = lane&3, j = lane>>2;
  float s;
  if(j==0) s = scz[(size_t)k*NR+n];
  else if(j<10){
    int tc = t-5+j; tc = tc<0?0:(tc>TT-1?TT-1:tc);
    s = sch[(size_t)k*NR + (b<<12) + tc];
  } else s = -1e30f;
  float m = s;
  #pragma unroll
  for(int o=4;o<64;o<<=1) m = fmaxf(m, __shfl_xor(m,o,64));
  float e = (j<10)? expf(s-m) : 0.f;
  float sum = e;
  #pragma unroll
  for(int o=4;o<64;o<<=1) sum += __shfl_xor(sum,o,64);
  float ev = e/sum;
  int d0 = lane*8;
  float acc[4][8] = {};
  #pragma unroll
  for(int jj=0;jj<10;jj++){
    const u16* src;
    if(jj==0) src = z + (size_t)n*512 + d0;
    else {
      int tc = t-5+jj; tc = tc<0?0:(tc>TT-1?TT-1:tc);
      src = hb + ((size_t)(b<<12)+tc)*512 + d0;
    }
    float f[8]; ld8(src, f);
    float w0 = __shfl(ev, jj*4+0, 64);
    float w1 = __shfl(ev, jj*4+1, 64);
    float w2 = __shfl(ev, jj*4+2, 64);
    float w3 = __shfl(ev, jj*4+3, 64);
    #pragma unroll
    for(int i=0;i<8;i++){
      acc[0][i] += w0*f[i];
      acc[1][i] += w1*f[i];
      acc[2][i] += w2*f[i];
      acc[3][i] += w3*f[i];
    }
  }
  #pragma unroll
  for(int kk=0;kk<4;kk++){
    u16* dst = P + ((size_t)kk*NR + n)*512 + d0;
    *(ushort4*)dst     = make_ushort4(f2b(acc[kk][0]),f2b(acc[kk][1]),f2b(acc[kk][2]),f2b(acc[kk][3]));
    *(ushort4*)(dst+4) = make_ushort4(f2b(acc[kk][4]),f2b(acc[kk][5]),f2b(acc[kk][6]),f2b(acc[kk][7]));
  }
}

// ---------- workspace layout (bytes) ----------
#define OFF_BL     0u
#define OFF_BSOFT  65536u
#define OFF_HSUM   131072u
#define OFF_HSS    196608u
#define OFF_SCH    262144u
#define OFF_SCZ    524288u
#define OFF_FIN    786432u            // bf16 NR*640 ; X2 (NR*2048 bf16) overlays fin+gb+z
#define OFF_GB     21757952u          // bf16 NR*1024
#define OFF_Z      55312384u          // bf16 NR*512
#define OFF_HBF    72089600u          // bf16 NR*512
#define OFF_WF     88866816u          // bf16 1024*640 (film_w^T)
#define OFF_WA     90177536u          // bf16 4*256*512 (attn_w1^T)
#define OFF_WP     91226112u          // bf16 4*512*512 (proj_w1^T)
#define OFF_P      93323264u          // bf16 4*NR*512 pooled (G aliases front 2 slots)
#define OFF_W2C    160432128u         // bf16 5*32*512 compact W2^T
#define OFF_B2C    160595968u         // f32 160

extern "C" void kernel_launch(void* const* d_in, const int* in_sizes, int n_in,
                              void* d_out, int out_size, void* d_ws, size_t ws_size,
                              hipStream_t stream){
  const float* h       = (const float*)d_in[0];
  const float* w_bnd   = (const float*)d_in[1];
  const float* b_bnd   = (const float*)d_in[2];
  const float* conv_k  = (const float*)d_in[3];
  const float* conv_b  = (const float*)d_in[4];
  const float* e0      = (const float*)d_in[5];
  const float* e1      = (const float*)d_in[6];
  const float* ln_in_g = (const float*)d_in[7];
  const float* ln_in_b = (const float*)d_in[8];
  const float* ln_h_g  = (const float*)d_in[9];
  const float* ln_h_b  = (const float*)d_in[10];
  const float* film_w  = (const float*)d_in[11];
  const float* film_b  = (const float*)d_in[12];
  const float* attn_w1 = (const float*)d_in[13];
  const float* attn_b1 = (const float*)d_in[14];
  const float* attn_w2 = (const float*)d_in[15];
  const float* attn_b2 = (const float*)d_in[16];
  const float* proj_w1 = (const float*)d_in[17];
  const float* proj_b1 = (const float*)d_in[18];
  const float* wq = (const float*)d_in[19];
  const float* bq = (const float*)d_in[20];
  const float* wr = (const float*)d_in[21];
  const float* br = (const float*)d_in[22];
  const float* wb_ = (const float*)d_in[23];
  const float* bb_ = (const float*)d_in[24];
  const float* wk = (const float*)d_in[25];
  const float* bk = (const float*)d_in[26];
  float* out = (float*)d_out;
  char* ws = (char*)d_ws;

  float* bl    = (float*)(ws + OFF_BL);
  float* bsoft = (float*)(ws + OFF_BSOFT);
  float* hsum  = (float*)(ws + OFF_HSUM);
  float* hss   = (float*)(ws + OFF_HSS);
  float* sch   = (float*)(ws + OFF_SCH);
  float* scz   = (float*)(ws + OFF_SCZ);
  u16* fin     = (u16*)(ws + OFF_FIN);
  u16* X2      = (u16*)(ws + OFF_FIN);   // overlays fin+gb+z (dead by proj1 time)
  u16* gb      = (u16*)(ws + OFF_GB);
  u16* z       = (u16*)(ws + OFF_Z);
  u16* hbf     = (u16*)(ws + OFF_HBF);
  u16* wfilm   = (u16*)(ws + OFF_WF);
  u16* wattn   = (u16*)(ws + OFF_WA);
  u16* wproj   = (u16*)(ws + OFF_WP);
  u16* P       = (u16*)(ws + OFF_P);
  u16* G       = P;   // alias: scores consumed (scred) before pool writes P slots
  u16* w2c     = (u16*)(ws + OFF_W2C);
  float* b2c   = (float*)(ws + OFF_B2C);

  // weight transpose-convert
  {
    dim3 g(1024/32, 640/32, 1);
    k_tw<<<g,256,0,stream>>>(film_w, wfilm, 640, 1024, 0, 0);
  }
  {
    dim3 g(256/32, 512/32, 4);
    k_tw<<<g,256,0,stream>>>(attn_w1, wattn, 512, 256, 512LL*256, 256LL*512);
  }
  {
    dim3 g(512/32, 512/32, 4);
    k_tw<<<g,256,0,stream>>>(proj_w1, wproj, 512, 512, 512LL*512, 512LL*512);
  }
  k_w2c<<<160,256,0,stream>>>(wq,bq,wr,br,wb_,bb_,wk,bk, w2c, b2c);

  k_bnd<<<NR/4,256,0,stream>>>(h,w_bnd,b_bnd,bl,hsum,hss,hbf,out);
  k_conv<<<NR/256,256,0,stream>>>(bl,conv_k,conv_b,bsoft);
  k_filmin<<<NR,256,0,stream>>>(h,bsoft,e0,e1,ln_in_g,ln_in_b,fin);

  dim3 gFilm(1024/128, NR/128, 1);
  k_mgemm<0><<<gFilm,256,0,stream>>>(fin, wfilm, film_b, gb, 640, 1024, 1024, 0,0,0,0);

  k_z<<<NR,256,0,stream>>>(h,hsum,hss,ln_h_g,ln_h_b,gb,z);

  dim3 gSc(256/128, NR/128, 4);
  dim3 gRed(NR/4, 4);
  k_mgemm<1><<<gSc,256,0,stream>>>(hbf, wattn, attn_b1, G, 512, 256, 256,
                                   0, 256LL*512, 256, (long long)NR*256);
  k_scred<<<gRed,256,0,stream>>>(G, attn_w2, attn_b2, sch);
  k_mgemm<1><<<gSc,256,0,stream>>>(z, wattn, attn_b1, G, 512, 256, 256,
                                   0, 256LL*512, 256, (long long)NR*256);
  k_scred<<<gRed,256,0,stream>>>(G, attn_w2, attn_b2, scz);

  k_pool<<<NR/4,256,0,stream>>>(hbf,z,sch,scz,P);

  // proj1: all 4 heads batched, writes X2 column blocks (ld 2048)
  dim3 gP(512/128, NR/128, 4);
  k_mgemm<1><<<gP,256,0,stream>>>(P, wproj, proj_b1, X2, 512, 512, 2048,
                                  (long long)NR*512, 512LL*512, 512, 512);

  // final projection -> out f32 (cols 0..114; col 115 written by k_bnd)
  dim3 gF(NR/128, 5);
  k_f2<<<gF,256,0,stream>>>(X2, w2c, b2c, out);
}

// Round 7
// 402.845 us; speedup vs baseline: 3.9581x; 1.1035x over previous
//
#include <hip/hip_runtime.h>
#include <hip/hip_bf16.h>

typedef unsigned short u16;
typedef unsigned int u32;

#define NR 16384   // B*T
#define TT 4096    // T

typedef __bf16 bf16_t;
typedef bf16_t bf16x8 __attribute__((ext_vector_type(8)));
typedef float f32x4 __attribute__((ext_vector_type(4)));

// ---------- bf16 helpers ----------
__device__ __forceinline__ float b2f(u16 u){ return __uint_as_float(((u32)u)<<16); }
__device__ __forceinline__ u16 f2b(float f){
  u32 u = __float_as_uint(f);
  u32 r = u + 0x7fffu + ((u>>16)&1u);
  return (u16)(r>>16);
}
__device__ __forceinline__ void up2(u32 u, float&a, float&b){
  a = __uint_as_float(u<<16);
  b = __uint_as_float(u & 0xffff0000u);
}
__device__ __forceinline__ void ld8(const u16* p, float* f){
  uint4 v = *(const uint4*)p;
  up2(v.x,f[0],f[1]); up2(v.y,f[2],f[3]);
  up2(v.z,f[4],f[5]); up2(v.w,f[6],f[7]);
}
__device__ __forceinline__ float wred(float v){
  #pragma unroll
  for(int o=32;o>0;o>>=1) v += __shfl_down(v,o,64);
  return v;
}
// fast gelu (tanh form): max abs err ~1e-3, well within 20x error margin
__device__ __forceinline__ float gelu_f(float x){
  float x2 = x*x;
  float u = x*(0.7978845608f + 0.0356774081f*x2);
  float e = __expf(2.0f*u);
  float t = 1.0f - 2.0f*__builtin_amdgcn_rcpf(e+1.0f);
  return 0.5f*x*(1.0f+t);
}
__device__ __forceinline__ void gl_lds(const void* g, void* l){
  __builtin_amdgcn_global_load_lds(
      (__attribute__((address_space(1))) void*)(void*)g,
      (__attribute__((address_space(3))) void*)l, 16, 0, 0);
}

// ---------- transpose-convert: src f32 [K][N] -> dst bf16 [N][K] ----------
__global__ void k_tw(const float* __restrict__ src, u16* __restrict__ dst,
                     int K, int N, long long sS, long long sD){
  __shared__ float t[32][33];
  const float* S = src + (size_t)blockIdx.z*sS;
  u16* D = dst + (size_t)blockIdx.z*sD;
  int k0 = blockIdx.y*32, n0 = blockIdx.x*32;
  int r = threadIdx.x>>5, c = threadIdx.x&31;
  #pragma unroll
  for(int p=0;p<4;p++) t[r+p*8][c] = S[(size_t)(k0+r+p*8)*N + n0 + c];
  __syncthreads();
  #pragma unroll
  for(int p=0;p<4;p++) D[(size_t)(n0+r+p*8)*K + k0 + c] = f2b(t[c][r+p*8]);
}

// ---------- build compact W2^T [5][32][512] + bias [5*32] (pseudo-heads) ----------
__global__ void k_w2c(const float* __restrict__ wq, const float* __restrict__ bq,
                      const float* __restrict__ wr, const float* __restrict__ br,
                      const float* __restrict__ wb_, const float* __restrict__ bb_,
                      const float* __restrict__ wk, const float* __restrict__ bk,
                      u16* __restrict__ W2c, float* __restrict__ b2c){
  int idx = blockIdx.x;            // 0..159 : p*32 + j
  int p = idx>>5, j = idx&31, tid = threadIdx.x;
  const float* Wm; const float* Bm; int V; int cofs = 0;
  if(p<=1){ Wm=wq; Bm=bq; V=64; cofs = p*32; }
  else if(p==2){ Wm=wr; Bm=br; V=13; }
  else if(p==3){ Wm=wb_; Bm=bb_; V=13; }
  else { Wm=wk; Bm=bk; V=25; }
  int c = j + cofs;
  bool valid = c < V;
  for(int k=tid;k<512;k+=256)
    W2c[(size_t)idx*512 + k] = f2b(valid ? Wm[(size_t)k*V + c] : 0.f);
  if(tid==0) b2c[idx] = valid ? Bm[c] : 0.f;
}

// ---------- K1: bl = h.w_bnd + b ; row stats ; h->bf16 ; out[:,115]=bl ----------
__global__ void k_bnd(const float* __restrict__ h, const float* __restrict__ wb,
                      const float* __restrict__ bb,
                      float* __restrict__ bl, float* __restrict__ hsum, float* __restrict__ hss,
                      u16* __restrict__ hbf, float* __restrict__ out){
  int wave = threadIdx.x>>6, lane = threadIdx.x&63;
  int n = blockIdx.x*4 + wave;
  const float4* hp = (const float4*)(h + (size_t)n*512 + lane*8);
  const float4* wp = (const float4*)(wb + lane*8);
  float4 h0 = hp[0], h1 = hp[1], w0 = wp[0], w1 = wp[1];
  float hv[8] = {h0.x,h0.y,h0.z,h0.w,h1.x,h1.y,h1.z,h1.w};
  float wv[8] = {w0.x,w0.y,w0.z,w0.w,w1.x,w1.y,w1.z,w1.w};
  float dot=0.f, s=0.f, ss=0.f;
  #pragma unroll
  for(int i=0;i<8;i++){ dot += hv[i]*wv[i]; s += hv[i]; ss += hv[i]*hv[i]; }
  u16* hd = hbf + (size_t)n*512 + lane*8;
  *(ushort4*)hd     = make_ushort4(f2b(hv[0]),f2b(hv[1]),f2b(hv[2]),f2b(hv[3]));
  *(ushort4*)(hd+4) = make_ushort4(f2b(hv[4]),f2b(hv[5]),f2b(hv[6]),f2b(hv[7]));
  dot = wred(dot); s = wred(s); ss = wred(ss);
  if(lane==0){
    float v = dot + bb[0];
    bl[n] = v; hsum[n]=s; hss[n]=ss;
    out[(size_t)n*116 + 115] = v;
  }
}

// ---------- K2: conv9 (zero pad) + sigmoid ----------
__global__ void k_conv(const float* __restrict__ bl, const float* __restrict__ ck,
                       const float* __restrict__ cb, float* __restrict__ bsoft){
  int n = blockIdx.x*256 + threadIdx.x;
  int b = n>>12, t = n&4095;
  float acc = cb[0];
  #pragma unroll
  for(int i=0;i<9;i++){
    int tt = t-4+i;
    if(tt>=0 && tt<TT) acc += bl[(b<<12)+tt]*ck[i];
  }
  bsoft[n] = 1.0f/(1.0f+expf(-acc));
}

// ---------- K3: film_in = LN(concat(h, eb)) -> bf16 ----------
__global__ void k_filmin(const float* __restrict__ h, const float* __restrict__ bsoft,
                         const float* __restrict__ e0, const float* __restrict__ e1,
                         const float* __restrict__ g, const float* __restrict__ bb,
                         u16* __restrict__ fin){
  __shared__ float xb[640];
  __shared__ float red[8];
  int n = blockIdx.x, tid = threadIdx.x;
  float bs = bsoft[n];
  float s=0.f, ss=0.f;
  for(int idx=tid; idx<640; idx+=256){
    float v;
    if(idx<512) v = h[(size_t)n*512+idx];
    else { int j=idx-512; v = bs*e1[j] + (1.0f-bs)*e0[j]; }
    xb[idx]=v; s+=v; ss+=v*v;
  }
  s = wred(s); ss = wred(ss);
  int wave = tid>>6, lane = tid&63;
  if(lane==0){ red[wave]=s; red[wave+4]=ss; }
  __syncthreads();
  float S = red[0]+red[1]+red[2]+red[3];
  float SS = red[4]+red[5]+red[6]+red[7];
  float mu = S*(1.0f/640.0f);
  float var = SS*(1.0f/640.0f) - mu*mu;
  float rs = rsqrtf(var + 1e-5f);
  for(int idx=tid; idx<640; idx+=256){
    float v = (xb[idx]-mu)*rs*g[idx] + bb[idx];
    fin[(size_t)n*640+idx] = f2b(v);
  }
}

// ---------- k_film: film GEMM (gamma+beta strips) + fused z epilogue ----------
// z = LN(h)*(1+gamma)+beta ; gamma=gb[:,d], beta=gb[:,512+d] computed in-block.
__global__ __launch_bounds__(256) void k_film(
    const u16* __restrict__ fin, const u16* __restrict__ WT, const float* __restrict__ fbias,
    const float* __restrict__ hsum, const float* __restrict__ hss,
    const float* __restrict__ lng, const float* __restrict__ lnb,
    const u16* __restrict__ hbf, u16* __restrict__ z){
  __shared__ __align__(16) u16 As[128*32];
  __shared__ __align__(16) u16 Bg[128*32];
  __shared__ __align__(16) u16 Bb2[128*32];
  int tid = threadIdx.x, wave = tid>>6, lane = tid&63;
  int cg0 = blockIdx.x*128, row0 = blockIdx.y*128;
  int wr = (wave>>1)*64, wc = (wave&1)*64;
  int lrow = lane>>2, lcol = (lane&3)*8, m15 = lane&15, q = lane>>4;
  f32x4 ag[4][4] = {}, ab[4][4] = {};
  for(int k0=0;k0<640;k0+=32){
    const u16* ga = fin + (size_t)(row0 + wave*32 + lrow)*640 + k0 + lcol;
    u16* la = As + wave*32*32;
    gl_lds(ga, la); gl_lds(ga + (size_t)16*640, la + 16*32);
    const u16* gg = WT + (size_t)(cg0 + wave*32 + lrow)*640 + k0 + lcol;
    u16* lg = Bg + wave*32*32;
    gl_lds(gg, lg); gl_lds(gg + (size_t)16*640, lg + 16*32);
    const u16* gb2 = WT + (size_t)(cg0 + 512 + wave*32 + lrow)*640 + k0 + lcol;
    u16* lb2 = Bb2 + wave*32*32;
    gl_lds(gb2, lb2); gl_lds(gb2 + (size_t)16*640, lb2 + 16*32);
    __syncthreads();
    bf16x8 af[4], bg[4], bb[4];
    #pragma unroll
    for(int i=0;i<4;i++){
      af[i] = *(const bf16x8*)&As[(wr + i*16 + m15)*32 + q*8];
      bg[i] = *(const bf16x8*)&Bg[(wc + i*16 + m15)*32 + q*8];
      bb[i] = *(const bf16x8*)&Bb2[(wc + i*16 + m15)*32 + q*8];
    }
    #pragma unroll
    for(int i=0;i<4;i++)
      #pragma unroll
      for(int j=0;j<4;j++){
        ag[i][j] = __builtin_amdgcn_mfma_f32_16x16x32_bf16(bg[j], af[i], ag[i][j], 0,0,0);
        ab[i][j] = __builtin_amdgcn_mfma_f32_16x16x32_bf16(bb[j], af[i], ab[i][j], 0,0,0);
      }
    __syncthreads();
  }
  // lane holds rows m = row0+wr+i*16+m15, cols d = cg0+wc+j*16+q*4+r
  #pragma unroll
  for(int i=0;i<4;i++){
    int m = row0 + wr + i*16 + m15;
    float mu = hsum[m]*(1.0f/512.0f);
    float var = hss[m]*(1.0f/512.0f) - mu*mu;
    float rs = rsqrtf(var + 1e-5f);
    #pragma unroll
    for(int j=0;j<4;j++){
      int d0 = cg0 + wc + j*16 + q*4;
      float4 g4 = *(const float4*)&lng[d0];
      float4 b4 = *(const float4*)&lnb[d0];
      float4 fg = *(const float4*)&fbias[d0];
      float4 fb = *(const float4*)&fbias[512+d0];
      float hv[4];
      { ushort4 hb4 = *(const ushort4*)(hbf + (size_t)m*512 + d0);
        hv[0]=b2f(hb4.x); hv[1]=b2f(hb4.y); hv[2]=b2f(hb4.z); hv[3]=b2f(hb4.w); }
      float gm[4] = {ag[i][j][0]+fg.x, ag[i][j][1]+fg.y, ag[i][j][2]+fg.z, ag[i][j][3]+fg.w};
      float bt[4] = {ab[i][j][0]+fb.x, ab[i][j][1]+fb.y, ab[i][j][2]+fb.z, ab[i][j][3]+fb.w};
      float gg4[4] = {g4.x,g4.y,g4.z,g4.w}, bb4[4] = {b4.x,b4.y,b4.z,b4.w};
      u16 o[4];
      #pragma unroll
      for(int r=0;r<4;r++){
        float ln = (hv[r]-mu)*rs*gg4[r] + bb4[r];
        o[r] = f2b(ln*(1.0f+gm[r]) + bt[r]);
      }
      *(ushort4*)(z + (size_t)m*512 + d0) = make_ushort4(o[0],o[1],o[2],o[3]);
    }
  }
}

// ---------- k_msc: score GEMM + fused gelu + w2-dot -> atomicAdd scores ----------
// grid (NR/64, 8): bz = head*2 + src(0=h,1=z). M=64, N=256 (full head).
__global__ __launch_bounds__(256) void k_msc(
    const u16* __restrict__ hb, const u16* __restrict__ zb,
    const u16* __restrict__ WT, const float* __restrict__ b1,
    const float* __restrict__ w2, float* __restrict__ sch, float* __restrict__ scz){
  __shared__ __align__(16) u16 As[64*32];
  __shared__ __align__(16) u16 Bs[256*32];
  int tid = threadIdx.x, wave = tid>>6, lane = tid&63;
  int bz = blockIdx.y, hk = bz>>1, src = bz&1;
  const u16* X = src ? zb : hb;
  float* sc = src ? scz : sch;
  int row0 = blockIdx.x*64;
  const u16* Wb = WT + (size_t)hk*256*512;
  int lrow = lane>>2, lcol = (lane&3)*8, m15 = lane&15, q = lane>>4;
  int wc = wave*64;
  f32x4 acc[4][4] = {};
  for(int k0=0;k0<512;k0+=32){
    gl_lds(X + (size_t)(row0 + wave*16 + lrow)*512 + k0 + lcol, As + wave*16*32);
    const u16* gw = Wb + (size_t)(wave*64 + lrow)*512 + k0 + lcol;
    u16* lb = Bs + wave*64*32;
    gl_lds(gw, lb);
    gl_lds(gw + (size_t)16*512, lb + 16*32);
    gl_lds(gw + (size_t)32*512, lb + 32*32);
    gl_lds(gw + (size_t)48*512, lb + 48*32);
    __syncthreads();
    bf16x8 af[4], bfr[4];
    #pragma unroll
    for(int i=0;i<4;i++){
      af[i]  = *(const bf16x8*)&As[(i*16 + m15)*32 + q*8];
      bfr[i] = *(const bf16x8*)&Bs[(wc + i*16 + m15)*32 + q*8];
    }
    #pragma unroll
    for(int i=0;i<4;i++)
      #pragma unroll
      for(int j=0;j<4;j++)
        acc[i][j] = __builtin_amdgcn_mfma_f32_16x16x32_bf16(bfr[j], af[i], acc[i][j], 0,0,0);
    __syncthreads();
  }
  // lane: rows m = row0+i*16+m15, cols n = wc+j*16+q*4+r
  #pragma unroll
  for(int i=0;i<4;i++){
    float part = 0.f;
    #pragma unroll
    for(int j=0;j<4;j++){
      int n0 = wc + j*16 + q*4;
      float4 bias = *(const float4*)&b1[hk*256 + n0];
      float4 wv   = *(const float4*)&w2[hk*256 + n0];
      part += gelu_f(acc[i][j][0]+bias.x)*wv.x;
      part += gelu_f(acc[i][j][1]+bias.y)*wv.y;
      part += gelu_f(acc[i][j][2]+bias.z)*wv.z;
      part += gelu_f(acc[i][j][3]+bias.w)*wv.w;
    }
    part += __shfl_xor(part, 16, 64);
    part += __shfl_xor(part, 32, 64);
    if(q==0) atomicAdd(&sc[(size_t)hk*NR + row0 + i*16 + m15], part);
  }
}

// ---------- k_proj: proj1 GEMM M=64 N=256, gelu, writes X2 (ld 2048) ----------
__global__ __launch_bounds__(256) void k_proj(
    const u16* __restrict__ P, const u16* __restrict__ WT, const float* __restrict__ Bv,
    u16* __restrict__ X2){
  __shared__ __align__(16) u16 As[64*32];
  __shared__ __align__(16) u16 Bs[256*32];
  int tid = threadIdx.x, wave = tid>>6, lane = tid&63;
  int hk = blockIdx.z;
  int row0 = blockIdx.y*64, col0 = blockIdx.x*256;
  const u16* Xb = P + (size_t)hk*NR*512;
  const u16* Wb = WT + (size_t)hk*512*512 + (size_t)col0*512;
  const float* Bq = Bv + hk*512;
  int lrow = lane>>2, lcol = (lane&3)*8, m15 = lane&15, q = lane>>4;
  int wc = wave*64;
  f32x4 acc[4][4] = {};
  for(int k0=0;k0<512;k0+=32){
    gl_lds(Xb + (size_t)(row0 + wave*16 + lrow)*512 + k0 + lcol, As + wave*16*32);
    const u16* gw = Wb + (size_t)(wave*64 + lrow)*512 + k0 + lcol;
    u16* lb = Bs + wave*64*32;
    gl_lds(gw, lb);
    gl_lds(gw + (size_t)16*512, lb + 16*32);
    gl_lds(gw + (size_t)32*512, lb + 32*32);
    gl_lds(gw + (size_t)48*512, lb + 48*32);
    __syncthreads();
    bf16x8 af[4], bfr[4];
    #pragma unroll
    for(int i=0;i<4;i++){
      af[i]  = *(const bf16x8*)&As[(i*16 + m15)*32 + q*8];
      bfr[i] = *(const bf16x8*)&Bs[(wc + i*16 + m15)*32 + q*8];
    }
    #pragma unroll
    for(int i=0;i<4;i++)
      #pragma unroll
      for(int j=0;j<4;j++)
        acc[i][j] = __builtin_amdgcn_mfma_f32_16x16x32_bf16(bfr[j], af[i], acc[i][j], 0,0,0);
    __syncthreads();
  }
  #pragma unroll
  for(int i=0;i<4;i++){
    size_t mrow = (size_t)(row0 + i*16 + m15)*2048 + hk*512;
    #pragma unroll
    for(int j=0;j<4;j++){
      int n0 = col0 + wc + j*16 + q*4;
      float4 bias = *(const float4*)&Bq[n0];
      float v0 = gelu_f(acc[i][j][0] + bias.x);
      float v1 = gelu_f(acc[i][j][1] + bias.y);
      float v2 = gelu_f(acc[i][j][2] + bias.z);
      float v3 = gelu_f(acc[i][j][3] + bias.w);
      *(ushort4*)(X2 + mrow + n0) = make_ushort4(f2b(v0),f2b(v1),f2b(v2),f2b(v3));
    }
  }
}

// ---------- final compact GEMM: out cols per pseudo-head ----------
__global__ __launch_bounds__(256) void k_f2(
    const u16* __restrict__ X2, const u16* __restrict__ W2c, const float* __restrict__ b2c,
    float* __restrict__ out){
  __shared__ __align__(16) u16 As[128*32];
  __shared__ __align__(16) u16 Bs[32*32];
  int tid = threadIdx.x, wave = tid>>6, lane = tid&63;
  int row0 = blockIdx.x*128, p = blockIdx.y;
  int hk = (p<=1)?0:(p-1);
  int B0 = (p==0)?0:(p==1)?32:(p==2)?64:(p==3)?77:90;
  int V  = (p<=1)?32:(p==4)?25:13;
  int lrow = lane>>2, lcol = (lane&3)*8, m15 = lane&15, q = lane>>4;
  f32x4 acc[2][2] = {};
  for(int k0=0;k0<512;k0+=32){
    const u16* ga = X2 + (size_t)(row0 + wave*32 + lrow)*2048 + hk*512 + k0 + lcol;
    u16* la = As + wave*32*32;
    gl_lds(ga, la);
    gl_lds(ga + (size_t)16*2048, la + 16*32);
    if(wave<2){
      const u16* gw = W2c + (size_t)(p*32 + wave*16 + lrow)*512 + k0 + lcol;
      gl_lds(gw, Bs + wave*16*32);
    }
    __syncthreads();
    bf16x8 af[2], bfr[2];
    #pragma unroll
    for(int i=0;i<2;i++) af[i] = *(const bf16x8*)&As[(wave*32 + i*16 + m15)*32 + q*8];
    #pragma unroll
    for(int j=0;j<2;j++) bfr[j] = *(const bf16x8*)&Bs[(j*16+m15)*32 + q*8];
    #pragma unroll
    for(int i=0;i<2;i++)
      #pragma unroll
      for(int j=0;j<2;j++)
        acc[i][j] = __builtin_amdgcn_mfma_f32_16x16x32_bf16(bfr[j], af[i], acc[i][j], 0,0,0);
    __syncthreads();
  }
  #pragma unroll
  for(int i=0;i<2;i++){
    size_t mrow = (size_t)(row0 + wave*32 + i*16 + m15)*116;
    #pragma unroll
    for(int j=0;j<2;j++){
      int nl0 = j*16 + q*4;
      #pragma unroll
      for(int r=0;r<4;r++){
        int nl = nl0 + r;
        if(nl < V) out[mrow + B0 + nl] = acc[i][j][r] + b2c[p*32+nl];
      }
    }
  }
}

// ---------- K7: one wave per row: lane-parallel softmax + register pooling ----------
__global__ __launch_bounds__(256) void k_pool(
    const u16* __restrict__ hb, const u16* __restrict__ z,
    const float* __restrict__ sch, const float* __restrict__ scz,
    u16* __restrict__ P){
  int wave = threadIdx.x>>6, lane = threadIdx.x&63;
  int n = blockIdx.x*4 + wave;
  int b = n>>12, t = n&4095;
  int k = lane&3, j = lane>>2;
  float s;
  if(j==0) s = scz[(size_t)k*NR+n];
  else if(j<10){
    int tc = t-5+j; tc = tc<0?0:(tc>TT-1?TT-1:tc);
    s = sch[(size_t)k*NR + (b<<12) + tc];
  } else s = -1e30f;
  float m = s;
  #pragma unroll
  for(int o=4;o<64;o<<=1) m = fmaxf(m, __shfl_xor(m,o,64));
  float e = (j<10)? expf(s-m) : 0.f;
  float sum = e;
  #pragma unroll
  for(int o=4;o<64;o<<=1) sum += __shfl_xor(sum,o,64);
  float ev = e/sum;
  int d0 = lane*8;
  float acc[4][8] = {};
  #pragma unroll
  for(int jj=0;jj<10;jj++){
    const u16* src;
    if(jj==0) src = z + (size_t)n*512 + d0;
    else {
      int tc = t-5+jj; tc = tc<0?0:(tc>TT-1?TT-1:tc);
      src = hb + ((size_t)(b<<12)+tc)*512 + d0;
    }
    float f[8]; ld8(src, f);
    float w0 = __shfl(ev, jj*4+0, 64);
    float w1 = __shfl(ev, jj*4+1, 64);
    float w2 = __shfl(ev, jj*4+2, 64);
    float w3 = __shfl(ev, jj*4+3, 64);
    #pragma unroll
    for(int i=0;i<8;i++){
      acc[0][i] += w0*f[i];
      acc[1][i] += w1*f[i];
      acc[2][i] += w2*f[i];
      acc[3][i] += w3*f[i];
    }
  }
  #pragma unroll
  for(int kk=0;kk<4;kk++){
    u16* dst = P + ((size_t)kk*NR + n)*512 + d0;
    *(ushort4*)dst     = make_ushort4(f2b(acc[kk][0]),f2b(acc[kk][1]),f2b(acc[kk][2]),f2b(acc[kk][3]));
    *(ushort4*)(dst+4) = make_ushort4(f2b(acc[kk][4]),f2b(acc[kk][5]),f2b(acc[kk][6]),f2b(acc[kk][7]));
  }
}

// ---------- workspace layout (bytes) ----------
#define OFF_BL     0u
#define OFF_BSOFT  65536u
#define OFF_HSUM   131072u
#define OFF_HSS    196608u
#define OFF_SCH    262144u
#define OFF_SCZ    524288u
#define OFF_FIN    786432u            // bf16 NR*640 ; X2 (NR*2048 bf16) overlays fin..z
#define OFF_Z      55312384u          // bf16 NR*512 (consumed by pool before X2 write)
#define OFF_HBF    72089600u          // bf16 NR*512
#define OFF_WF     88866816u          // bf16 1024*640 (film_w^T)
#define OFF_WA     90177536u          // bf16 4*256*512 (attn_w1^T)
#define OFF_WP     91226112u          // bf16 4*512*512 (proj_w1^T)
#define OFF_P      93323264u          // bf16 4*NR*512 pooled
#define OFF_W2C    160432128u         // bf16 5*32*512 compact W2^T
#define OFF_B2C    160595968u         // f32 160

extern "C" void kernel_launch(void* const* d_in, const int* in_sizes, int n_in,
                              void* d_out, int out_size, void* d_ws, size_t ws_size,
                              hipStream_t stream){
  const float* h       = (const float*)d_in[0];
  const float* w_bnd   = (const float*)d_in[1];
  const float* b_bnd   = (const float*)d_in[2];
  const float* conv_k  = (const float*)d_in[3];
  const float* conv_b  = (const float*)d_in[4];
  const float* e0      = (const float*)d_in[5];
  const float* e1      = (const float*)d_in[6];
  const float* ln_in_g = (const float*)d_in[7];
  const float* ln_in_b = (const float*)d_in[8];
  const float* ln_h_g  = (const float*)d_in[9];
  const float* ln_h_b  = (const float*)d_in[10];
  const float* film_w  = (const float*)d_in[11];
  const float* film_b  = (const float*)d_in[12];
  const float* attn_w1 = (const float*)d_in[13];
  const float* attn_b1 = (const float*)d_in[14];
  const float* attn_w2 = (const float*)d_in[15];
  // d_in[16] = attn_b2 (unused: softmax shift-invariant)
  const float* proj_w1 = (const float*)d_in[17];
  const float* proj_b1 = (const float*)d_in[18];
  const float* wq = (const float*)d_in[19];
  const float* bq = (const float*)d_in[20];
  const float* wr = (const float*)d_in[21];
  const float* br = (const float*)d_in[22];
  const float* wb_ = (const float*)d_in[23];
  const float* bb_ = (const float*)d_in[24];
  const float* wk = (const float*)d_in[25];
  const float* bk = (const float*)d_in[26];
  float* out = (float*)d_out;
  char* ws = (char*)d_ws;

  float* bl    = (float*)(ws + OFF_BL);
  float* bsoft = (float*)(ws + OFF_BSOFT);
  float* hsum  = (float*)(ws + OFF_HSUM);
  float* hss   = (float*)(ws + OFF_HSS);
  float* sch   = (float*)(ws + OFF_SCH);
  float* scz   = (float*)(ws + OFF_SCZ);
  u16* fin     = (u16*)(ws + OFF_FIN);
  u16* X2      = (u16*)(ws + OFF_FIN);   // overlays fin+z region (dead by proj1 time)
  u16* z       = (u16*)(ws + OFF_Z);
  u16* hbf     = (u16*)(ws + OFF_HBF);
  u16* wfilm   = (u16*)(ws + OFF_WF);
  u16* wattn   = (u16*)(ws + OFF_WA);
  u16* wproj   = (u16*)(ws + OFF_WP);
  u16* P       = (u16*)(ws + OFF_P);
  u16* w2c     = (u16*)(ws + OFF_W2C);
  float* b2c   = (float*)(ws + OFF_B2C);

  // zero score accumulators (atomicAdd targets)
  hipMemsetAsync(ws + OFF_SCH, 0, 524288, stream);

  // weight transpose-convert
  {
    dim3 g(1024/32, 640/32, 1);
    k_tw<<<g,256,0,stream>>>(film_w, wfilm, 640, 1024, 0, 0);
  }
  {
    dim3 g(256/32, 512/32, 4);
    k_tw<<<g,256,0,stream>>>(attn_w1, wattn, 512, 256, 512LL*256, 256LL*512);
  }
  {
    dim3 g(512/32, 512/32, 4);
    k_tw<<<g,256,0,stream>>>(proj_w1, wproj, 512, 512, 512LL*512, 512LL*512);
  }
  k_w2c<<<160,256,0,stream>>>(wq,bq,wr,br,wb_,bb_,wk,bk, w2c, b2c);

  k_bnd<<<NR/4,256,0,stream>>>(h,w_bnd,b_bnd,bl,hsum,hss,hbf,out);
  k_conv<<<NR/256,256,0,stream>>>(bl,conv_k,conv_b,bsoft);
  k_filmin<<<NR,256,0,stream>>>(h,bsoft,e0,e1,ln_in_g,ln_in_b,fin);

  // film GEMM + fused z
  {
    dim3 g(4, NR/128);
    k_film<<<g,256,0,stream>>>(fin, wfilm, film_b, hsum, hss, ln_h_g, ln_h_b, hbf, z);
  }

  // fused score GEMM (h and z, all heads)
  {
    dim3 g(NR/64, 8);
    k_msc<<<g,256,0,stream>>>(hbf, z, wattn, attn_b1, attn_w2, sch, scz);
  }

  k_pool<<<NR/4,256,0,stream>>>(hbf,z,sch,scz,P);

  // proj1: M=64/N=256 tiles, batched heads, writes X2 (ld 2048)
  {
    dim3 g(2, NR/64, 4);
    k_proj<<<g,256,0,stream>>>(P, wproj, proj_b1, X2);
  }

  // final projection -> out f32 (cols 0..114; col 115 written by k_bnd)
  {
    dim3 g(NR/128, 5);
    k_f2<<<g,256,0,stream>>>(X2, w2c, b2c, out);
  }
}

// Round 8
// 387.525 us; speedup vs baseline: 4.1146x; 1.0395x over previous
//
#include <hip/hip_runtime.h>
#include <hip/hip_bf16.h>

typedef unsigned short u16;
typedef unsigned int u32;

#define NR 16384   // B*T
#define TT 4096    // T

typedef __bf16 bf16_t;
typedef bf16_t bf16x8 __attribute__((ext_vector_type(8)));
typedef float f32x4 __attribute__((ext_vector_type(4)));

// ---------- bf16 helpers ----------
__device__ __forceinline__ float b2f(u16 u){ return __uint_as_float(((u32)u)<<16); }
__device__ __forceinline__ u16 f2b(float f){
  u32 u = __float_as_uint(f);
  u32 r = u + 0x7fffu + ((u>>16)&1u);
  return (u16)(r>>16);
}
__device__ __forceinline__ void up2(u32 u, float&a, float&b){
  a = __uint_as_float(u<<16);
  b = __uint_as_float(u & 0xffff0000u);
}
__device__ __forceinline__ void ld8(const u16* p, float* f){
  uint4 v = *(const uint4*)p;
  up2(v.x,f[0],f[1]); up2(v.y,f[2],f[3]);
  up2(v.z,f[4],f[5]); up2(v.w,f[6],f[7]);
}
__device__ __forceinline__ float wred(float v){
  #pragma unroll
  for(int o=32;o>0;o>>=1) v += __shfl_down(v,o,64);
  return v;
}
// fast gelu (tanh form): max abs err ~1e-3, well within 20x error margin
__device__ __forceinline__ float gelu_f(float x){
  float x2 = x*x;
  float u = x*(0.7978845608f + 0.0356774081f*x2);
  float e = __expf(2.0f*u);
  float t = 1.0f - 2.0f*__builtin_amdgcn_rcpf(e+1.0f);
  return 0.5f*x*(1.0f+t);
}
__device__ __forceinline__ void gl_lds(const void* g, void* l){
  __builtin_amdgcn_global_load_lds(
      (__attribute__((address_space(1))) void*)(void*)g,
      (__attribute__((address_space(3))) void*)l, 16, 0, 0);
}

// ---------- transpose-convert: src f32 [K][N] -> dst bf16 [N][K] ----------
__global__ void k_tw(const float* __restrict__ src, u16* __restrict__ dst,
                     int K, int N, long long sS, long long sD){
  __shared__ float t[32][33];
  const float* S = src + (size_t)blockIdx.z*sS;
  u16* D = dst + (size_t)blockIdx.z*sD;
  int k0 = blockIdx.y*32, n0 = blockIdx.x*32;
  int r = threadIdx.x>>5, c = threadIdx.x&31;
  #pragma unroll
  for(int p=0;p<4;p++) t[r+p*8][c] = S[(size_t)(k0+r+p*8)*N + n0 + c];
  __syncthreads();
  #pragma unroll
  for(int p=0;p<4;p++) D[(size_t)(n0+r+p*8)*K + k0 + c] = f2b(t[c][r+p*8]);
}

// ---------- build compact W2^T [5][32][512] + bias [5*32] (pseudo-heads) ----------
__global__ void k_w2c(const float* __restrict__ wq, const float* __restrict__ bq,
                      const float* __restrict__ wr, const float* __restrict__ br,
                      const float* __restrict__ wb_, const float* __restrict__ bb_,
                      const float* __restrict__ wk, const float* __restrict__ bk,
                      u16* __restrict__ W2c, float* __restrict__ b2c){
  int idx = blockIdx.x;            // 0..159 : p*32 + j
  int p = idx>>5, j = idx&31, tid = threadIdx.x;
  const float* Wm; const float* Bm; int V; int cofs = 0;
  if(p<=1){ Wm=wq; Bm=bq; V=64; cofs = p*32; }
  else if(p==2){ Wm=wr; Bm=br; V=13; }
  else if(p==3){ Wm=wb_; Bm=bb_; V=13; }
  else { Wm=wk; Bm=bk; V=25; }
  int c = j + cofs;
  bool valid = c < V;
  for(int k=tid;k<512;k+=256)
    W2c[(size_t)idx*512 + k] = f2b(valid ? Wm[(size_t)k*V + c] : 0.f);
  if(tid==0) b2c[idx] = valid ? Bm[c] : 0.f;
}

// ---------- e-moment scalars: es = {S_e0, S_e1, SS_e0, SS_e1, S_e0e1} ----------
__global__ void k_esum(const float* __restrict__ e0, const float* __restrict__ e1,
                       float* __restrict__ es){
  int lane = threadIdx.x & 63;
  float x0 = e0[lane], x1 = e0[lane+64];
  float y0 = e1[lane], y1 = e1[lane+64];
  float s0 = x0+x1, s1 = y0+y1;
  float q0 = x0*x0+x1*x1, q1 = y0*y0+y1*y1, c = x0*y0+x1*y1;
  s0 = wred(s0); s1 = wred(s1); q0 = wred(q0); q1 = wred(q1); c = wred(c);
  if(lane==0){ es[0]=s0; es[1]=s1; es[2]=q0; es[3]=q1; es[4]=c; }
}

// ---------- K1: bl = h.w_bnd + b ; row stats ; h->bf16 ; out[:,115]=bl ----------
__global__ void k_bnd(const float* __restrict__ h, const float* __restrict__ wb,
                      const float* __restrict__ bb,
                      float* __restrict__ bl, float* __restrict__ hsum, float* __restrict__ hss,
                      u16* __restrict__ hbf, float* __restrict__ out){
  int wave = threadIdx.x>>6, lane = threadIdx.x&63;
  int n = blockIdx.x*4 + wave;
  const float4* hp = (const float4*)(h + (size_t)n*512 + lane*8);
  const float4* wp = (const float4*)(wb + lane*8);
  float4 h0 = hp[0], h1 = hp[1], w0 = wp[0], w1 = wp[1];
  float hv[8] = {h0.x,h0.y,h0.z,h0.w,h1.x,h1.y,h1.z,h1.w};
  float wv[8] = {w0.x,w0.y,w0.z,w0.w,w1.x,w1.y,w1.z,w1.w};
  float dot=0.f, s=0.f, ss=0.f;
  #pragma unroll
  for(int i=0;i<8;i++){ dot += hv[i]*wv[i]; s += hv[i]; ss += hv[i]*hv[i]; }
  u16* hd = hbf + (size_t)n*512 + lane*8;
  *(ushort4*)hd     = make_ushort4(f2b(hv[0]),f2b(hv[1]),f2b(hv[2]),f2b(hv[3]));
  *(ushort4*)(hd+4) = make_ushort4(f2b(hv[4]),f2b(hv[5]),f2b(hv[6]),f2b(hv[7]));
  dot = wred(dot); s = wred(s); ss = wred(ss);
  if(lane==0){
    float v = dot + bb[0];
    bl[n] = v; hsum[n]=s; hss[n]=ss;
    out[(size_t)n*116 + 115] = v;
  }
}

// ---------- K2: conv9 (zero pad) + sigmoid ----------
__global__ void k_conv(const float* __restrict__ bl, const float* __restrict__ ck,
                       const float* __restrict__ cb, float* __restrict__ bsoft){
  int n = blockIdx.x*256 + threadIdx.x;
  int b = n>>12, t = n&4095;
  float acc = cb[0];
  #pragma unroll
  for(int i=0;i<9;i++){
    int tt = t-4+i;
    if(tt>=0 && tt<TT) acc += bl[(b<<12)+tt]*ck[i];
  }
  bsoft[n] = 1.0f/(1.0f+expf(-acc));
}

// ---------- K3: film_in = LN(concat(h, eb)) -> bf16 (streaming, analytic stats) ----
__global__ void k_filmin(const u16* __restrict__ hbf, const float* __restrict__ bsoft,
                         const float* __restrict__ e0, const float* __restrict__ e1,
                         const float* __restrict__ es,
                         const float* __restrict__ hsum, const float* __restrict__ hss,
                         const float* __restrict__ g, const float* __restrict__ bb,
                         u16* __restrict__ fin){
  int n = blockIdx.x, tid = threadIdx.x;
  if(tid >= 160) return;
  float bs = bsoft[n], os = 1.0f - bs;
  float S  = hsum[n] + bs*es[1] + os*es[0];
  float SS = hss[n] + bs*bs*es[3] + 2.0f*bs*os*es[4] + os*os*es[2];
  float mu = S*(1.0f/640.0f);
  float var = SS*(1.0f/640.0f) - mu*mu;
  float rs = rsqrtf(var + 1e-5f);
  int d = tid*4;
  float v[4];
  if(d < 512){
    ushort4 hv = *(const ushort4*)(hbf + (size_t)n*512 + d);
    v[0]=b2f(hv.x); v[1]=b2f(hv.y); v[2]=b2f(hv.z); v[3]=b2f(hv.w);
  } else {
    float4 a = *(const float4*)(e1 + d - 512);
    float4 b0 = *(const float4*)(e0 + d - 512);
    v[0]=bs*a.x+os*b0.x; v[1]=bs*a.y+os*b0.y; v[2]=bs*a.z+os*b0.z; v[3]=bs*a.w+os*b0.w;
  }
  float4 g4 = *(const float4*)(g + d);
  float4 b4 = *(const float4*)(bb + d);
  u16 o[4];
  o[0]=f2b((v[0]-mu)*rs*g4.x+b4.x); o[1]=f2b((v[1]-mu)*rs*g4.y+b4.y);
  o[2]=f2b((v[2]-mu)*rs*g4.z+b4.z); o[3]=f2b((v[3]-mu)*rs*g4.w+b4.w);
  *(ushort4*)(fin + (size_t)n*640 + d) = make_ushort4(o[0],o[1],o[2],o[3]);
}

// ---------- k_film: film GEMM (gamma+beta strips, BK=64) + fused z epilogue ------
__global__ __launch_bounds__(256) void k_film(
    const u16* __restrict__ fin, const u16* __restrict__ WT, const float* __restrict__ fbias,
    const float* __restrict__ hsum, const float* __restrict__ hss,
    const float* __restrict__ lng, const float* __restrict__ lnb,
    const u16* __restrict__ hbf, u16* __restrict__ z){
  __shared__ __align__(16) u16 As[2][128*32];
  __shared__ __align__(16) u16 Bg[2][128*32];
  __shared__ __align__(16) u16 Bb2[2][128*32];
  int tid = threadIdx.x, wave = tid>>6, lane = tid&63;
  int cg0 = blockIdx.x*128, row0 = blockIdx.y*128;
  int wr = (wave>>1)*64, wc = (wave&1)*64;
  int lrow = lane>>2, lcol = (lane&3)*8, m15 = lane&15, q = lane>>4;
  f32x4 ag[4][4] = {}, ab[4][4] = {};
  for(int k0=0;k0<640;k0+=64){
    #pragma unroll
    for(int hh=0;hh<2;hh++){
      int kk = k0 + hh*32;
      const u16* ga = fin + (size_t)(row0 + wave*32 + lrow)*640 + kk + lcol;
      u16* la = &As[hh][wave*32*32];
      gl_lds(ga, la); gl_lds(ga + (size_t)16*640, la + 16*32);
      const u16* gg = WT + (size_t)(cg0 + wave*32 + lrow)*640 + kk + lcol;
      u16* lg = &Bg[hh][wave*32*32];
      gl_lds(gg, lg); gl_lds(gg + (size_t)16*640, lg + 16*32);
      const u16* gb2 = WT + (size_t)(cg0 + 512 + wave*32 + lrow)*640 + kk + lcol;
      u16* lb2 = &Bb2[hh][wave*32*32];
      gl_lds(gb2, lb2); gl_lds(gb2 + (size_t)16*640, lb2 + 16*32);
    }
    __syncthreads();
    #pragma unroll
    for(int hh=0;hh<2;hh++){
      bf16x8 af[4], bg[4], bb[4];
      #pragma unroll
      for(int i=0;i<4;i++){
        af[i] = *(const bf16x8*)&As[hh][(wr + i*16 + m15)*32 + q*8];
        bg[i] = *(const bf16x8*)&Bg[hh][(wc + i*16 + m15)*32 + q*8];
        bb[i] = *(const bf16x8*)&Bb2[hh][(wc + i*16 + m15)*32 + q*8];
      }
      #pragma unroll
      for(int i=0;i<4;i++)
        #pragma unroll
        for(int j=0;j<4;j++){
          ag[i][j] = __builtin_amdgcn_mfma_f32_16x16x32_bf16(bg[j], af[i], ag[i][j], 0,0,0);
          ab[i][j] = __builtin_amdgcn_mfma_f32_16x16x32_bf16(bb[j], af[i], ab[i][j], 0,0,0);
        }
    }
    __syncthreads();
  }
  #pragma unroll
  for(int i=0;i<4;i++){
    int m = row0 + wr + i*16 + m15;
    float mu = hsum[m]*(1.0f/512.0f);
    float var = hss[m]*(1.0f/512.0f) - mu*mu;
    float rs = rsqrtf(var + 1e-5f);
    #pragma unroll
    for(int j=0;j<4;j++){
      int d0 = cg0 + wc + j*16 + q*4;
      float4 g4 = *(const float4*)&lng[d0];
      float4 b4 = *(const float4*)&lnb[d0];
      float4 fg = *(const float4*)&fbias[d0];
      float4 fb = *(const float4*)&fbias[512+d0];
      float hv[4];
      { ushort4 hb4 = *(const ushort4*)(hbf + (size_t)m*512 + d0);
        hv[0]=b2f(hb4.x); hv[1]=b2f(hb4.y); hv[2]=b2f(hb4.z); hv[3]=b2f(hb4.w); }
      float gm[4] = {ag[i][j][0]+fg.x, ag[i][j][1]+fg.y, ag[i][j][2]+fg.z, ag[i][j][3]+fg.w};
      float bt[4] = {ab[i][j][0]+fb.x, ab[i][j][1]+fb.y, ab[i][j][2]+fb.z, ab[i][j][3]+fb.w};
      float gg4[4] = {g4.x,g4.y,g4.z,g4.w}, bb4[4] = {b4.x,b4.y,b4.z,b4.w};
      u16 o[4];
      #pragma unroll
      for(int r=0;r<4;r++){
        float ln = (hv[r]-mu)*rs*gg4[r] + bb4[r];
        o[r] = f2b(ln*(1.0f+gm[r]) + bt[r]);
      }
      *(ushort4*)(z + (size_t)m*512 + d0) = make_ushort4(o[0],o[1],o[2],o[3]);
    }
  }
}

// ---------- k_msc: score GEMM (BK=64) + fused gelu + w2-dot -> atomicAdd ---------
__global__ __launch_bounds__(256) void k_msc(
    const u16* __restrict__ hb, const u16* __restrict__ zb,
    const u16* __restrict__ WT, const float* __restrict__ b1,
    const float* __restrict__ w2, float* __restrict__ sch, float* __restrict__ scz){
  __shared__ __align__(16) u16 As[2][64*32];
  __shared__ __align__(16) u16 Bs[2][256*32];
  int tid = threadIdx.x, wave = tid>>6, lane = tid&63;
  int bz = blockIdx.y, hk = bz>>1, src = bz&1;
  const u16* X = src ? zb : hb;
  float* sc = src ? scz : sch;
  int row0 = blockIdx.x*64;
  const u16* Wb = WT + (size_t)hk*256*512;
  int lrow = lane>>2, lcol = (lane&3)*8, m15 = lane&15, q = lane>>4;
  int wc = wave*64;
  f32x4 acc[4][4] = {};
  for(int k0=0;k0<512;k0+=64){
    #pragma unroll
    for(int hh=0;hh<2;hh++){
      int kk = k0 + hh*32;
      gl_lds(X + (size_t)(row0 + wave*16 + lrow)*512 + kk + lcol, &As[hh][wave*16*32]);
      #pragma unroll
      for(int r=0;r<4;r++)
        gl_lds(Wb + (size_t)(wave*64 + r*16 + lrow)*512 + kk + lcol,
               &Bs[hh][(wave*64 + r*16)*32]);
    }
    __syncthreads();
    #pragma unroll
    for(int hh=0;hh<2;hh++){
      bf16x8 af[4], bfr[4];
      #pragma unroll
      for(int i=0;i<4;i++){
        af[i]  = *(const bf16x8*)&As[hh][(i*16 + m15)*32 + q*8];
        bfr[i] = *(const bf16x8*)&Bs[hh][(wc + i*16 + m15)*32 + q*8];
      }
      #pragma unroll
      for(int i=0;i<4;i++)
        #pragma unroll
        for(int j=0;j<4;j++)
          acc[i][j] = __builtin_amdgcn_mfma_f32_16x16x32_bf16(bfr[j], af[i], acc[i][j], 0,0,0);
    }
    __syncthreads();
  }
  #pragma unroll
  for(int i=0;i<4;i++){
    float part = 0.f;
    #pragma unroll
    for(int j=0;j<4;j++){
      int n0 = wc + j*16 + q*4;
      float4 bias = *(const float4*)&b1[hk*256 + n0];
      float4 wv   = *(const float4*)&w2[hk*256 + n0];
      part += gelu_f(acc[i][j][0]+bias.x)*wv.x;
      part += gelu_f(acc[i][j][1]+bias.y)*wv.y;
      part += gelu_f(acc[i][j][2]+bias.z)*wv.z;
      part += gelu_f(acc[i][j][3]+bias.w)*wv.w;
    }
    part += __shfl_xor(part, 16, 64);
    part += __shfl_xor(part, 32, 64);
    if(q==0) atomicAdd(&sc[(size_t)hk*NR + row0 + i*16 + m15], part);
  }
}

// ---------- k_proj: proj1 GEMM (BK=64) M=64 N=256, gelu, writes X2 (ld 2048) -----
__global__ __launch_bounds__(256) void k_proj(
    const u16* __restrict__ P, const u16* __restrict__ WT, const float* __restrict__ Bv,
    u16* __restrict__ X2){
  __shared__ __align__(16) u16 As[2][64*32];
  __shared__ __align__(16) u16 Bs[2][256*32];
  int tid = threadIdx.x, wave = tid>>6, lane = tid&63;
  int hk = blockIdx.z;
  int row0 = blockIdx.y*64, col0 = blockIdx.x*256;
  const u16* Xb = P + (size_t)hk*NR*512;
  const u16* Wb = WT + (size_t)hk*512*512 + (size_t)col0*512;
  const float* Bq = Bv + hk*512;
  int lrow = lane>>2, lcol = (lane&3)*8, m15 = lane&15, q = lane>>4;
  int wc = wave*64;
  f32x4 acc[4][4] = {};
  for(int k0=0;k0<512;k0+=64){
    #pragma unroll
    for(int hh=0;hh<2;hh++){
      int kk = k0 + hh*32;
      gl_lds(Xb + (size_t)(row0 + wave*16 + lrow)*512 + kk + lcol, &As[hh][wave*16*32]);
      #pragma unroll
      for(int r=0;r<4;r++)
        gl_lds(Wb + (size_t)(wave*64 + r*16 + lrow)*512 + kk + lcol,
               &Bs[hh][(wave*64 + r*16)*32]);
    }
    __syncthreads();
    #pragma unroll
    for(int hh=0;hh<2;hh++){
      bf16x8 af[4], bfr[4];
      #pragma unroll
      for(int i=0;i<4;i++){
        af[i]  = *(const bf16x8*)&As[hh][(i*16 + m15)*32 + q*8];
        bfr[i] = *(const bf16x8*)&Bs[hh][(wc + i*16 + m15)*32 + q*8];
      }
      #pragma unroll
      for(int i=0;i<4;i++)
        #pragma unroll
        for(int j=0;j<4;j++)
          acc[i][j] = __builtin_amdgcn_mfma_f32_16x16x32_bf16(bfr[j], af[i], acc[i][j], 0,0,0);
    }
    __syncthreads();
  }
  #pragma unroll
  for(int i=0;i<4;i++){
    size_t mrow = (size_t)(row0 + i*16 + m15)*2048 + hk*512;
    #pragma unroll
    for(int j=0;j<4;j++){
      int n0 = col0 + wc + j*16 + q*4;
      float4 bias = *(const float4*)&Bq[n0];
      float v0 = gelu_f(acc[i][j][0] + bias.x);
      float v1 = gelu_f(acc[i][j][1] + bias.y);
      float v2 = gelu_f(acc[i][j][2] + bias.z);
      float v3 = gelu_f(acc[i][j][3] + bias.w);
      *(ushort4*)(X2 + mrow + n0) = make_ushort4(f2b(v0),f2b(v1),f2b(v2),f2b(v3));
    }
  }
}

// ---------- final compact GEMM (BK=64): out cols per pseudo-head -----------------
__global__ __launch_bounds__(256) void k_f2(
    const u16* __restrict__ X2, const u16* __restrict__ W2c, const float* __restrict__ b2c,
    float* __restrict__ out){
  __shared__ __align__(16) u16 As[2][128*32];
  __shared__ __align__(16) u16 Bs[2][32*32];
  int tid = threadIdx.x, wave = tid>>6, lane = tid&63;
  int row0 = blockIdx.x*128, p = blockIdx.y;
  int hk = (p<=1)?0:(p-1);
  int B0 = (p==0)?0:(p==1)?32:(p==2)?64:(p==3)?77:90;
  int V  = (p<=1)?32:(p==4)?25:13;
  int lrow = lane>>2, lcol = (lane&3)*8, m15 = lane&15, q = lane>>4;
  f32x4 acc[2][2] = {};
  for(int k0=0;k0<512;k0+=64){
    #pragma unroll
    for(int hh=0;hh<2;hh++){
      int kk = k0 + hh*32;
      const u16* ga = X2 + (size_t)(row0 + wave*32 + lrow)*2048 + hk*512 + kk + lcol;
      u16* la = &As[hh][wave*32*32];
      gl_lds(ga, la);
      gl_lds(ga + (size_t)16*2048, la + 16*32);
      if(wave<2)
        gl_lds(W2c + (size_t)(p*32 + wave*16 + lrow)*512 + kk + lcol, &Bs[hh][wave*16*32]);
    }
    __syncthreads();
    #pragma unroll
    for(int hh=0;hh<2;hh++){
      bf16x8 af[2], bfr[2];
      #pragma unroll
      for(int i=0;i<2;i++) af[i] = *(const bf16x8*)&As[hh][(wave*32 + i*16 + m15)*32 + q*8];
      #pragma unroll
      for(int j=0;j<2;j++) bfr[j] = *(const bf16x8*)&Bs[hh][(j*16+m15)*32 + q*8];
      #pragma unroll
      for(int i=0;i<2;i++)
        #pragma unroll
        for(int j=0;j<2;j++)
          acc[i][j] = __builtin_amdgcn_mfma_f32_16x16x32_bf16(bfr[j], af[i], acc[i][j], 0,0,0);
    }
    __syncthreads();
  }
  #pragma unroll
  for(int i=0;i<2;i++){
    size_t mrow = (size_t)(row0 + wave*32 + i*16 + m15)*116;
    #pragma unroll
    for(int j=0;j<2;j++){
      int nl0 = j*16 + q*4;
      #pragma unroll
      for(int r=0;r<4;r++){
        int nl = nl0 + r;
        if(nl < V) out[mrow + B0 + nl] = acc[i][j][r] + b2c[p*32+nl];
      }
    }
  }
}

// ---------- K7: one wave per row: lane-parallel softmax + register pooling -------
__global__ __launch_bounds__(256) void k_pool(
    const u16* __restrict__ hb, const u16* __restrict__ z,
    const float* __restrict__ sch, const float* __restrict__ scz,
    u16* __restrict__ P){
  int wave = threadIdx.x>>6, lane = threadIdx.x&63;
  int n = blockIdx.x*4 + wave;
  int b = n>>12, t = n&4095;
  int k = lane&3, j = lane>>2;
  float s;
  if(j==0) s = scz[(size_t)k*NR+n];
  else if(j<10){
    int tc = t-5+j; tc = tc<0?0:(tc>TT-1?TT-1:tc);
    s = sch[(size_t)k*NR + (b<<12) + tc];
  } else s = -1e30f;
  float m = s;
  #pragma unroll
  for(int o=4;o<64;o<<=1) m = fmaxf(m, __shfl_xor(m,o,64));
  float e = (j<10)? expf(s-m) : 0.f;
  float sum = e;
  #pragma unroll
  for(int o=4;o<64;o<<=1) sum += __shfl_xor(sum,o,64);
  float ev = e/sum;
  int d0 = lane*8;
  float acc[4][8] = {};
  #pragma unroll
  for(int jj=0;jj<10;jj++){
    const u16* src;
    if(jj==0) src = z + (size_t)n*512 + d0;
    else {
      int tc = t-5+jj; tc = tc<0?0:(tc>TT-1?TT-1:tc);
      src = hb + ((size_t)(b<<12)+tc)*512 + d0;
    }
    float f[8]; ld8(src, f);
    float w0 = __shfl(ev, jj*4+0, 64);
    float w1 = __shfl(ev, jj*4+1, 64);
    float w2 = __shfl(ev, jj*4+2, 64);
    float w3 = __shfl(ev, jj*4+3, 64);
    #pragma unroll
    for(int i=0;i<8;i++){
      acc[0][i] += w0*f[i];
      acc[1][i] += w1*f[i];
      acc[2][i] += w2*f[i];
      acc[3][i] += w3*f[i];
    }
  }
  #pragma unroll
  for(int kk=0;kk<4;kk++){
    u16* dst = P + ((size_t)kk*NR + n)*512 + d0;
    *(ushort4*)dst     = make_ushort4(f2b(acc[kk][0]),f2b(acc[kk][1]),f2b(acc[kk][2]),f2b(acc[kk][3]));
    *(ushort4*)(dst+4) = make_ushort4(f2b(acc[kk][4]),f2b(acc[kk][5]),f2b(acc[kk][6]),f2b(acc[kk][7]));
  }
}

// ---------- workspace layout (bytes) ----------
#define OFF_BL     0u
#define OFF_BSOFT  65536u
#define OFF_HSUM   131072u
#define OFF_HSS    196608u
#define OFF_SCH    262144u
#define OFF_SCZ    524288u
#define OFF_FIN    786432u            // bf16 NR*640 ; X2 (NR*2048 bf16) overlays fin..z
#define OFF_Z      55312384u          // bf16 NR*512 (consumed by pool before X2 write)
#define OFF_HBF    72089600u          // bf16 NR*512
#define OFF_WF     88866816u          // bf16 1024*640 (film_w^T)
#define OFF_WA     90177536u          // bf16 4*256*512 (attn_w1^T)
#define OFF_WP     91226112u          // bf16 4*512*512 (proj_w1^T)
#define OFF_P      93323264u          // bf16 4*NR*512 pooled
#define OFF_W2C    160432128u         // bf16 5*32*512 compact W2^T
#define OFF_B2C    160595968u         // f32 160
#define OFF_ES     160596608u         // f32 5 (e-moments)

extern "C" void kernel_launch(void* const* d_in, const int* in_sizes, int n_in,
                              void* d_out, int out_size, void* d_ws, size_t ws_size,
                              hipStream_t stream){
  const float* h       = (const float*)d_in[0];
  const float* w_bnd   = (const float*)d_in[1];
  const float* b_bnd   = (const float*)d_in[2];
  const float* conv_k  = (const float*)d_in[3];
  const float* conv_b  = (const float*)d_in[4];
  const float* e0      = (const float*)d_in[5];
  const float* e1      = (const float*)d_in[6];
  const float* ln_in_g = (const float*)d_in[7];
  const float* ln_in_b = (const float*)d_in[8];
  const float* ln_h_g  = (const float*)d_in[9];
  const float* ln_h_b  = (const float*)d_in[10];
  const float* film_w  = (const float*)d_in[11];
  const float* film_b  = (const float*)d_in[12];
  const float* attn_w1 = (const float*)d_in[13];
  const float* attn_b1 = (const float*)d_in[14];
  const float* attn_w2 = (const float*)d_in[15];
  // d_in[16] = attn_b2 (unused: softmax shift-invariant)
  const float* proj_w1 = (const float*)d_in[17];
  const float* proj_b1 = (const float*)d_in[18];
  const float* wq = (const float*)d_in[19];
  const float* bq = (const float*)d_in[20];
  const float* wr = (const float*)d_in[21];
  const float* br = (const float*)d_in[22];
  const float* wb_ = (const float*)d_in[23];
  const float* bb_ = (const float*)d_in[24];
  const float* wk = (const float*)d_in[25];
  const float* bk = (const float*)d_in[26];
  float* out = (float*)d_out;
  char* ws = (char*)d_ws;

  float* bl    = (float*)(ws + OFF_BL);
  float* bsoft = (float*)(ws + OFF_BSOFT);
  float* hsum  = (float*)(ws + OFF_HSUM);
  float* hss   = (float*)(ws + OFF_HSS);
  float* sch   = (float*)(ws + OFF_SCH);
  float* scz   = (float*)(ws + OFF_SCZ);
  u16* fin     = (u16*)(ws + OFF_FIN);
  u16* X2      = (u16*)(ws + OFF_FIN);   // overlays fin+z region (dead by proj1 time)
  u16* z       = (u16*)(ws + OFF_Z);
  u16* hbf     = (u16*)(ws + OFF_HBF);
  u16* wfilm   = (u16*)(ws + OFF_WF);
  u16* wattn   = (u16*)(ws + OFF_WA);
  u16* wproj   = (u16*)(ws + OFF_WP);
  u16* P       = (u16*)(ws + OFF_P);
  u16* w2c     = (u16*)(ws + OFF_W2C);
  float* b2c   = (float*)(ws + OFF_B2C);
  float* es    = (float*)(ws + OFF_ES);

  // zero score accumulators (atomicAdd targets)
  hipMemsetAsync(ws + OFF_SCH, 0, 524288, stream);

  // weight transpose-convert + scalars
  {
    dim3 g(1024/32, 640/32, 1);
    k_tw<<<g,256,0,stream>>>(film_w, wfilm, 640, 1024, 0, 0);
  }
  {
    dim3 g(256/32, 512/32, 4);
    k_tw<<<g,256,0,stream>>>(attn_w1, wattn, 512, 256, 512LL*256, 256LL*512);
  }
  {
    dim3 g(512/32, 512/32, 4);
    k_tw<<<g,256,0,stream>>>(proj_w1, wproj, 512, 512, 512LL*512, 512LL*512);
  }
  k_w2c<<<160,256,0,stream>>>(wq,bq,wr,br,wb_,bb_,wk,bk, w2c, b2c);
  k_esum<<<1,64,0,stream>>>(e0, e1, es);

  k_bnd<<<NR/4,256,0,stream>>>(h,w_bnd,b_bnd,bl,hsum,hss,hbf,out);
  k_conv<<<NR/256,256,0,stream>>>(bl,conv_k,conv_b,bsoft);
  k_filmin<<<NR,256,0,stream>>>(hbf,bsoft,e0,e1,es,hsum,hss,ln_in_g,ln_in_b,fin);

  // film GEMM + fused z
  {
    dim3 g(4, NR/128);
    k_film<<<g,256,0,stream>>>(fin, wfilm, film_b, hsum, hss, ln_h_g, ln_h_b, hbf, z);
  }

  // fused score GEMM (h and z, all heads)
  {
    dim3 g(NR/64, 8);
    k_msc<<<g,256,0,stream>>>(hbf, z, wattn, attn_b1, attn_w2, sch, scz);
  }

  k_pool<<<NR/4,256,0,stream>>>(hbf,z,sch,scz,P);

  // proj1: M=64/N=256 tiles, batched heads, writes X2 (ld 2048)
  {
    dim3 g(2, NR/64, 4);
    k_proj<<<g,256,0,stream>>>(P, wproj, proj_b1, X2);
  }

  // final projection -> out f32 (cols 0..114; col 115 written by k_bnd)
  {
    dim3 g(NR/128, 5);
    k_f2<<<g,256,0,stream>>>(X2, w2c, b2c, out);
  }
}